// Round 7
// baseline (621.896 us; speedup 1.0000x reference)
//
#include <hip/hip_runtime.h>
#include <hip/hip_bf16.h>

#define NN 100000
#define NE 1600000
#define DD 128
#define SD 384
#define BB 1024
#define ECAP 65536
#define L1CAP 36864
#define L1ECAP 655360
#define NCH 8
#define CH  12500          // NCH*CH == NN
#define DEGB 48
#define ESH 33336          // mult of 8; DEGB*ESH >= NE
#define SLOTCH 12288
#define NSCH 3
#define PB 64
#define SCN (NSCH*SLOTCH)  // 36864
#define GSC 2048
#define CAPS 782           // ceil(NE/GSC)
#define CHN 391            // ceil(NN/256)
#define PR 8               // rows per k_proj block

typedef unsigned int u32;
typedef unsigned short u16;
typedef unsigned long long u64;

__device__ __forceinline__ float bf2f(u16 x){ return __uint_as_float(((u32)x) << 16); }
__device__ __forceinline__ u16 f2bf(float f){
  u32 u = __float_as_uint(f);
  return (u16)((u + 0x7FFFu + ((u >> 16) & 1u)) >> 16);
}

// ---- s1p/s2p = s @ w_proj : 8-row blocked, transposed LDS -----------------
__global__ __launch_bounds__(128) void k_proj(const float* __restrict__ s1, const float* __restrict__ s2,
                                              const float* __restrict__ wp,
                                              float* __restrict__ s1p, float* __restrict__ s2p){
  __shared__ float srow[SD*10];
  int t = threadIdx.x;
  int row0 = blockIdx.x * PR;                 // 0..2047, no s1/s2 straddle (BB%8==0)
  const float* sb = (row0 < BB) ? (s1 + (size_t)row0*SD) : (s2 + (size_t)(row0-BB)*SD);
  float* spb      = (row0 < BB) ? (s1p + (size_t)row0*DD) : (s2p + (size_t)(row0-BB)*DD);
  #pragma unroll
  for (int r = 0; r < PR; ++r)
    for (int k = t; k < SD; k += 128) srow[k*10 + r] = sb[r*SD + k];
  __syncthreads();
  float a0=0,a1=0,a2=0,a3=0,a4=0,a5=0,a6=0,a7=0;
  #pragma unroll 2
  for (int k = 0; k < SD; ++k){
    float w = wp[k*DD + t];
    float2 p0 = *(const float2*)&srow[k*10+0];
    float2 p1 = *(const float2*)&srow[k*10+2];
    float2 p2 = *(const float2*)&srow[k*10+4];
    float2 p3 = *(const float2*)&srow[k*10+6];
    a0 += p0.x*w; a1 += p0.y*w; a2 += p1.x*w; a3 += p1.y*w;
    a4 += p2.x*w; a5 += p2.y*w; a6 += p3.x*w; a7 += p3.y*w;
  }
  spb[0*DD+t]=a0; spb[1*DD+t]=a1; spb[2*DD+t]=a2; spb[3*DD+t]=a3;
  spb[4*DD+t]=a4; spb[5*DD+t]=a5; spb[6*DD+t]=a6; spb[7*DD+t]=a7;
}

// ---- flag S nodes + owner priority ----------------------------------------
__global__ void k_mark(const int* __restrict__ idx1, const int* __restrict__ idx2,
                       int* __restrict__ owner, int* __restrict__ slot1, int* __restrict__ slotS){
  int j = blockIdx.x*blockDim.x + threadIdx.x;
  if (j >= 2*BB) return;
  int n = (j < BB) ? idx1[j] : idx2[j - BB];
  atomicMax(&owner[n], j);
  slotS[n] = -2;
  slot1[n] = -2;
}

// ---- deg partial histograms: dense coalesced dump, NO global atomics ------
__global__ __launch_bounds__(256) void k_degp(const int* __restrict__ edst, const float* __restrict__ ew,
                                              float* __restrict__ partial){
  __shared__ float part[CH];
  int c  = blockIdx.x / DEGB;
  int r  = blockIdx.x % DEGB;
  int lo = c * CH;
  for (int i = threadIdx.x; i < CH; i += 256) part[i] = 0.f;
  __syncthreads();
  int e0 = r * ESH;
  int e1 = e0 + ESH; if (e1 > NE) e1 = NE;
  for (int e = e0 + threadIdx.x*4; e < e1; e += 256*4){
    int4   d4 = *(const int4*)(edst + e);
    float4 w4 = *(const float4*)(ew + e);
    unsigned q;
    q = (unsigned)(d4.x - lo); if (q < CH) atomicAdd(&part[q], w4.x);
    q = (unsigned)(d4.y - lo); if (q < CH) atomicAdd(&part[q], w4.y);
    q = (unsigned)(d4.z - lo); if (q < CH) atomicAdd(&part[q], w4.z);
    q = (unsigned)(d4.w - lo); if (q < CH) atomicAdd(&part[q], w4.w);
  }
  __syncthreads();
  float* dst = partial + ((size_t)(c*DEGB + r))*CH;
  for (int i = threadIdx.x; i < CH; i += 256) dst[i] = part[i];
}

// ---- dinv[n] = rsqrt(1 + sum_r partial[c][r][i]) --------------------------
__global__ __launch_bounds__(256) void k_dinv(const float* __restrict__ partial, float* __restrict__ dinv){
  int n = blockIdx.x*blockDim.x + threadIdx.x;
  if (n >= NN) return;
  int c = n / CH, i = n - c*CH;
  const float* p = partial + ((size_t)c*DEGB)*CH + i;
  float s = 0.f;
  #pragma unroll
  for (int r = 0; r < DEGB; ++r) s += p[(size_t)r*CH];
  dinv[n] = rsqrtf(s + 1.0f);
}

// ---- pass A: per-block-slice S-edge collection ----------------------------
__global__ __launch_bounds__(256) void k_scansel(const int* __restrict__ esrc, const int* __restrict__ edst,
    const int* __restrict__ slotS, int* __restrict__ slot1,
    int* __restrict__ selCnt, int* __restrict__ slcA){
  __shared__ int lcnt;
  __shared__ int buf[CAPS];
  int b = blockIdx.x, tid = threadIdx.x;
  if (tid == 0) lcnt = 0;
  __syncthreads();
  int lo = b*CAPS, hi = lo + CAPS; if (hi > NE) hi = NE;
  for (int e = lo + tid; e < hi; e += 256){
    int d = edst[e];
    if (slotS[d] != -1){
      int p = atomicAdd(&lcnt, 1);
      buf[p] = e;
      slot1[esrc[e]] = -2;
    }
  }
  __syncthreads();
  int c = lcnt;
  if (tid == 0) selCnt[b] = c;
  for (int i = tid; i < c; i += 256) slcA[lo + i] = buf[i];
}

// ---- pass B: per-block-slice L1-edge collection ---------------------------
__global__ __launch_bounds__(256) void k_scanl1(const int* __restrict__ edst, const int* __restrict__ slot1,
    int* __restrict__ l1Cnt, int* __restrict__ slcB){
  __shared__ int lcnt;
  __shared__ int buf[CAPS];
  int b = blockIdx.x, tid = threadIdx.x;
  if (tid == 0) lcnt = 0;
  __syncthreads();
  int lo = b*CAPS, hi = lo + CAPS; if (hi > NE) hi = NE;
  for (int e = lo + tid; e < hi; e += 256){
    if (slot1[edst[e]] >= 0){
      int p = atomicAdd(&lcnt, 1);
      buf[p] = e;
    }
  }
  __syncthreads();
  int c = lcnt;
  if (tid == 0) l1Cnt[b] = c;
  for (int i = tid; i < c; i += 256) slcB[lo + i] = buf[i];
}

// ---- count flags per node-chunk -------------------------------------------
__global__ __launch_bounds__(256) void k_cflag(const int* __restrict__ slot1, const int* __restrict__ slotS,
                                               int* __restrict__ fc1, int* __restrict__ fcS){
  __shared__ int r1[256], r2[256];
  int b = blockIdx.x;
  int lo = b*CHN, hi = lo + CHN; if (hi > NN) hi = NN;
  int c1 = 0, cS = 0;
  for (int n = lo + threadIdx.x; n < hi; n += 256){
    if (slot1[n] == -2) c1++;
    if (slotS[n] == -2) cS++;
  }
  r1[threadIdx.x] = c1; r2[threadIdx.x] = cS;
  __syncthreads();
  for (int s = 128; s > 0; s >>= 1){
    if (threadIdx.x < s){ r1[threadIdx.x] += r1[threadIdx.x+s]; r2[threadIdx.x] += r2[threadIdx.x+s]; }
    __syncthreads();
  }
  if (threadIdx.x == 0){ fc1[b] = r1[0]; fcS[b] = r2[0]; }
}

// ---- assign slots positionally --------------------------------------------
__global__ __launch_bounds__(64) void k_asn(const int* __restrict__ fc1, const int* __restrict__ fcS,
    int* __restrict__ slot1, int* __restrict__ slotS, int* __restrict__ list1, int* __restrict__ cnt){
  int b = blockIdx.x, lane = threadIdx.x;
  int s1 = 0, sS = 0;
  for (int q = lane; q < b; q += 64){ s1 += fc1[q]; sS += fcS[q]; }
  #pragma unroll
  for (int o = 1; o < 64; o <<= 1){ s1 += __shfl_xor(s1, o); sS += __shfl_xor(sS, o); }
  int base1 = s1, baseS = sS;
  int lo = b*CHN, hi = lo + CHN; if (hi > NN) hi = NN;
  for (int g = lo; g < hi; g += 64){
    int n = g + lane;
    bool f1 = (n < hi) && (slot1[n] == -2);
    bool fS = (n < hi) && (slotS[n] == -2);
    u64 m1 = __ballot(f1);
    u64 mS = __ballot(fS);
    if (f1){
      int sl = base1 + __popcll(m1 & ((1ull << lane) - 1ull));
      if (sl < L1CAP){ slot1[n] = sl; list1[sl] = n; } else slot1[n] = -3;
    }
    if (fS){
      int sl = baseS + __popcll(mS & ((1ull << lane) - 1ull));
      slotS[n] = (sl < 2*BB) ? sl : -3;
    }
    base1 += __popcll(m1);
    baseS += __popcll(mS);
  }
  if (b == 255 && lane == 0){ cnt[0] = base1; cnt[1] = baseS; }
}

// ---- two 2048-entry exclusive scans (grid = 2) ----------------------------
__global__ __launch_bounds__(1024) void k_escan2(const int* __restrict__ selCnt, int* __restrict__ selOff,
                                                 const int* __restrict__ l1Cnt, int* __restrict__ l1Off,
                                                 int* __restrict__ cnt){
  __shared__ int ts[1024];
  const int* in = (blockIdx.x == 0) ? selCnt : l1Cnt;
  int* out      = (blockIdx.x == 0) ? selOff : l1Off;
  int* cp       = cnt + (blockIdx.x == 0 ? 2 : 3);
  int tid = threadIdx.x;
  int a = in[2*tid], c = in[2*tid+1];
  int pair = a + c;
  ts[tid] = pair;
  __syncthreads();
  for (int o = 1; o < 1024; o <<= 1){
    int v = (tid >= o) ? ts[tid-o] : 0;
    __syncthreads();
    ts[tid] += v;
    __syncthreads();
  }
  int incl = ts[tid];
  int excl = incl - pair;
  out[2*tid]   = excl;
  out[2*tid+1] = excl + a;
  if (tid == 1023){ out[2048] = incl; *cp = incl; }
}

// ---- compact both slice lists (grid = 2*GSC) ------------------------------
__global__ __launch_bounds__(128) void k_compact(const int* __restrict__ slcA, const int* __restrict__ slcB,
    const int* __restrict__ selCnt, const int* __restrict__ selOff,
    const int* __restrict__ l1Cnt, const int* __restrict__ l1Off,
    const int* __restrict__ esrc, const int* __restrict__ edst, const float* __restrict__ ew,
    const float* __restrict__ dinv, const int* __restrict__ slot1,
    int* __restrict__ eS, int* __restrict__ eD, float* __restrict__ eWl,
    int* __restrict__ eL1s, int* __restrict__ eL1c, float* __restrict__ eL1w){
  int b = blockIdx.x;
  if (b < GSC){
    int cb = selCnt[b], off = selOff[b];
    for (int i = threadIdx.x; i < cb; i += 128){
      int o = off + i;
      if (o >= ECAP) break;
      int e = slcA[b*CAPS + i];
      eS[o] = esrc[e]; eD[o] = edst[e]; eWl[o] = ew[e];
    }
  } else {
    b -= GSC;
    int cb = l1Cnt[b], off = l1Off[b];
    for (int i = threadIdx.x; i < cb; i += 128){
      int o = off + i;
      if (o >= L1ECAP) break;
      int e = slcB[b*CAPS + i];
      int s = esrc[e];
      eL1s[o] = s;
      eL1c[o] = slot1[edst[e]];
      eL1w[o] = dinv[s]*ew[e];
    }
  }
}

// ---- per-block slot histograms --------------------------------------------
__global__ __launch_bounds__(256) void k_cnt1(const int* __restrict__ eL1c, const int* __restrict__ cnt,
    int* __restrict__ cnt1, int* __restrict__ blk){
  __shared__ int hist[SLOTCH];
  int chunk = blockIdx.x / PB, b = blockIdx.x % PB;
  int n1 = cnt[0]; if (n1 > L1CAP) n1 = L1CAP;
  int lo = chunk * SLOTCH;
  if (lo >= n1) return;
  int m1 = cnt[3]; if (m1 > L1ECAP) m1 = L1ECAP;
  int slice = (m1 + PB - 1) / PB;
  int e0 = b*slice, e1 = e0 + slice; if (e1 > m1) e1 = m1;
  for (int i = threadIdx.x; i < SLOTCH; i += 256) hist[i] = 0;
  __syncthreads();
  for (int i = e0 + threadIdx.x; i < e1; i += 256){
    unsigned rel = (unsigned)(eL1c[i] - lo);
    if (rel < SLOTCH) atomicAdd(&hist[rel], 1);
  }
  __syncthreads();
  int* bc = blk + ((size_t)(chunk*PB + b))*SLOTCH;
  for (int i = threadIdx.x; i < SLOTCH; i += 256){
    int v = hist[i];
    bc[i] = v;
    if (v) atomicAdd(&cnt1[lo + i], v);
  }
}

// ---- exclusive scan over SCN counts ---------------------------------------
__global__ __launch_bounds__(1024) void k_scanex(const int* __restrict__ cnt1, int* __restrict__ rowptr){
  __shared__ int tsum[1024];
  int tid = threadIdx.x;
  int loc[36];
  int base = tid*36;
  int run = 0;
  #pragma unroll
  for (int k = 0; k < 36; ++k){ int v = cnt1[base+k]; loc[k] = run; run += v; }
  tsum[tid] = run;
  __syncthreads();
  for (int off = 1; off < 1024; off <<= 1){
    int v = (tid >= off) ? tsum[tid-off] : 0;
    __syncthreads();
    tsum[tid] += v;
    __syncthreads();
  }
  int inc = tsum[tid];
  int excl = inc - run;
  #pragma unroll
  for (int k = 0; k < 36; ++k) rowptr[base+k] = excl + loc[k];
  if (tid == 1023) rowptr[SCN] = inc;
}

// ---- per-(block,slot) start offsets (in place) ----------------------------
__global__ void k_off(const int* __restrict__ cnt, const int* __restrict__ rowptr, int* __restrict__ blk){
  int slot = blockIdx.x*blockDim.x + threadIdx.x;
  if (slot >= SCN) return;
  int n1 = cnt[0]; if (n1 > L1CAP) n1 = L1CAP;
  int chunk = slot / SLOTCH, rel = slot % SLOTCH;
  if (chunk*SLOTCH >= n1) return;
  int running = rowptr[slot];
  for (int b = 0; b < PB; ++b){
    size_t idx = ((size_t)(chunk*PB + b))*SLOTCH + rel;
    int t = blk[idx];
    blk[idx] = running;
    running += t;
  }
}

// ---- place edges into CSR -------------------------------------------------
__global__ __launch_bounds__(256) void k_place(const int* __restrict__ eL1s, const int* __restrict__ eL1c,
    const float* __restrict__ eL1w, const int* __restrict__ cnt, const int* __restrict__ blk,
    int* __restrict__ eCs, float* __restrict__ eCw){
  __shared__ int cur[SLOTCH];
  int chunk = blockIdx.x / PB, b = blockIdx.x % PB;
  int n1 = cnt[0]; if (n1 > L1CAP) n1 = L1CAP;
  int lo = chunk * SLOTCH;
  if (lo >= n1) return;
  int m1 = cnt[3]; if (m1 > L1ECAP) m1 = L1ECAP;
  int slice = (m1 + PB - 1) / PB;
  int e0 = b*slice, e1 = e0 + slice; if (e1 > m1) e1 = m1;
  const int* bo = blk + ((size_t)(chunk*PB + b))*SLOTCH;
  for (int i = threadIdx.x; i < SLOTCH; i += 256) cur[i] = bo[i];
  __syncthreads();
  for (int i = e0 + threadIdx.x; i < e1; i += 256){
    int c = eL1c[i];
    unsigned rel = (unsigned)(c - lo);
    if (rel < SLOTCH){
      int pos = atomicAdd(&cur[rel], 1);
      eCs[pos] = eL1s[i];
      eCw[pos] = eL1w[i];
    }
  }
}

// ---- layer-1 aggregation, CSR owner-computes ------------------------------
__global__ __launch_bounds__(256) void k_agg1(const int* __restrict__ rowptr, const int* __restrict__ eCs,
    const float* __restrict__ eCw, const int* __restrict__ cnt, const int* __restrict__ list1,
    const float* __restrict__ dinv, const int* __restrict__ owner,
    const float* __restrict__ emb, const float* __restrict__ s1p, const float* __restrict__ s2p,
    float* __restrict__ agg1){
  int lane = threadIdx.x & 63;
  int wid  = (blockIdx.x*blockDim.x + threadIdx.x) >> 6;
  int nwv  = (gridDim.x*blockDim.x) >> 6;
  int n1 = cnt[0]; if (n1 > L1CAP) n1 = L1CAP;
  for (int c = wid; c < n1; c += nwv){
    int r0 = rowptr[c], r1 = rowptr[c+1];
    float ax = 0.f, ay = 0.f;
    for (int base = r0; base < r1; base += 64){
      int k = base + lane;
      bool valid = (k < r1);
      int   sv = valid ? eCs[k] : 0;
      float wv = valid ? eCw[k] : 0.f;
      int   ov = valid ? owner[sv] : 0;
      int m = r1 - base; if (m > 64) m = 64;
      for (int j = 0; j < m; ++j){
        int s    = __shfl(sv, j);
        float nw = __shfl(wv, j);
        int o    = __shfl(ov, j);
        const float* xp = (o < 0) ? (emb + (size_t)s*DD)
                        : (o < BB) ? (s1p + (size_t)o*DD) : (s2p + (size_t)(o-BB)*DD);
        float2 v = *(const float2*)(xp + lane*2);
        ax += nw*v.x; ay += nw*v.y;
      }
    }
    float dd = dinv[list1[c]];
    float2 res; res.x = ax*dd; res.y = ay*dd;
    *(float2*)(agg1 + (size_t)c*DD + lane*2) = res;
  }
}

// ---- h = relu((agg1 + self) @ w1), bf16 -----------------------------------
__global__ __launch_bounds__(128) void k_gemm1(const float* __restrict__ agg1, const int* __restrict__ list1,
    const int* __restrict__ cnt, const float* __restrict__ w1, const float* __restrict__ dinv,
    const int* __restrict__ owner, const float* __restrict__ emb,
    const float* __restrict__ s1p, const float* __restrict__ s2p,
    u16* __restrict__ hbuf){
  __shared__ float row[DD];
  int t = threadIdx.x;
  u32 wreg[DD/2];
  #pragma unroll
  for (int i = 0; i < DD/2; ++i){
    u32 lo = f2bf(w1[(2*i)*DD + t]);
    u32 hi = f2bf(w1[(2*i+1)*DD + t]);
    wreg[i] = lo | (hi << 16);
  }
  int n1 = cnt[0]; if (n1 > L1CAP) n1 = L1CAP;
  for (int sl = blockIdx.x; sl < n1; sl += gridDim.x){
    int n = list1[sl];
    int o = owner[n];
    float di = dinv[n];
    float xv;
    if (o < 0) xv = emb[(size_t)n*DD + t];
    else if (o < BB) xv = s1p[(size_t)o*DD + t];
    else xv = s2p[(size_t)(o-BB)*DD + t];
    __syncthreads();
    row[t] = agg1[(size_t)sl*DD + t] + di*di*xv;
    __syncthreads();
    float acc = 0.f;
    #pragma unroll
    for (int i = 0; i < DD/2; ++i){
      float2 rv = *(const float2*)&row[2*i];
      u32 w = wreg[i];
      acc += rv.x * bf2f((u16)w);
      acc += rv.y * bf2f((u16)(w >> 16));
    }
    hbuf[(size_t)sl*DD + t] = f2bf(fmaxf(acc, 0.f));
  }
}

// ---- mini-CSR over S-edges by dst slot (single block) ---------------------
__global__ __launch_bounds__(1024) void k_csr2(const int* __restrict__ eS, const int* __restrict__ eD,
    const float* __restrict__ eWl, const int* __restrict__ cnt,
    const int* __restrict__ slot1, const int* __restrict__ slotS, const float* __restrict__ dinv,
    int* __restrict__ rowptr2, int* __restrict__ e2i, float* __restrict__ e2w){
  __shared__ int hist[2048];
  __shared__ int ts[1024];
  int tid = threadIdx.x;
  int ne = cnt[2]; if (ne > ECAP) ne = ECAP;
  hist[2*tid] = 0; hist[2*tid+1] = 0;
  __syncthreads();
  for (int k = tid; k < ne; k += 1024){
    int sd = slotS[eD[k]];
    if (sd >= 0) atomicAdd(&hist[sd], 1);
  }
  __syncthreads();
  int a = hist[2*tid], b = hist[2*tid+1];
  int pair = a + b;
  ts[tid] = pair;
  __syncthreads();
  for (int o = 1; o < 1024; o <<= 1){
    int v = (tid >= o) ? ts[tid-o] : 0;
    __syncthreads();
    ts[tid] += v;
    __syncthreads();
  }
  int incl = ts[tid];
  int excl = incl - pair;
  rowptr2[2*tid]   = excl;
  rowptr2[2*tid+1] = excl + a;
  if (tid == 1023) rowptr2[2048] = incl;
  __syncthreads();
  hist[2*tid] = excl; hist[2*tid+1] = excl + a;   // cursors
  __syncthreads();
  for (int k = tid; k < ne; k += 1024){
    int d = eD[k];
    int sd = slotS[d];
    if (sd < 0) continue;
    int s = eS[k];
    int pos = atomicAdd(&hist[sd], 1);
    e2i[pos] = slot1[s];
    e2w[pos] = dinv[s]*dinv[d]*eWl[k];
  }
}

// ---- layer-2 aggregation, owner-computes ----------------------------------
__global__ __launch_bounds__(256) void k_agg2(const int* __restrict__ rowptr2, const int* __restrict__ e2i,
    const float* __restrict__ e2w, const int* __restrict__ cnt,
    const u16* __restrict__ hbuf, float* __restrict__ agg2){
  int lane = threadIdx.x & 63;
  int wid  = (blockIdx.x*blockDim.x + threadIdx.x) >> 6;
  int nwv  = (gridDim.x*blockDim.x) >> 6;
  int nS = cnt[1]; if (nS > 2*BB) nS = 2*BB;
  for (int c = wid; c < nS; c += nwv){
    int r0 = rowptr2[c], r1 = rowptr2[c+1];
    float ax = 0.f, ay = 0.f;
    for (int k = r0; k < r1; ++k){
      int i = e2i[k];
      if (i < 0) continue;
      float w = e2w[k];
      u32 p = *(const u32*)(hbuf + (size_t)i*DD + lane*2);
      ax += w*bf2f((u16)p);
      ay += w*bf2f((u16)(p >> 16));
    }
    float2 res; res.x = ax; res.y = ay;
    *(float2*)(agg2 + (size_t)c*DD + lane*2) = res;
  }
}

// ---- x_g = (agg2 + self) @ w2 ; out = 0.7*sp + 0.3*x_g --------------------
__global__ __launch_bounds__(128) void k_final(const int* __restrict__ idx1, const int* __restrict__ idx2,
    const float* __restrict__ s1p, const float* __restrict__ s2p,
    const float* __restrict__ agg2, const int* __restrict__ slot1, const int* __restrict__ slotS,
    const float* __restrict__ dinv, const u16* __restrict__ hbuf, const float* __restrict__ w2,
    float* __restrict__ out){
  __shared__ float row[DD];
  int t = threadIdx.x;
  u32 wreg[DD/2];
  #pragma unroll
  for (int i = 0; i < DD/2; ++i){
    u32 lo = f2bf(w2[(2*i)*DD + t]);
    u32 hi = f2bf(w2[(2*i+1)*DD + t]);
    wreg[i] = lo | (hi << 16);
  }
  for (int j = blockIdx.x; j < 2*BB; j += gridDim.x){
    int n = (j < BB) ? idx1[j] : idx2[j - BB];
    float di = dinv[n];
    int sl = slot1[n];
    float hv = (sl >= 0) ? bf2f(hbuf[(size_t)sl*DD + t]) : 0.f;
    __syncthreads();
    int ss = slotS[n];
    row[t] = (ss >= 0 ? agg2[(size_t)ss*DD + t] : 0.f) + di*di*hv;
    __syncthreads();
    float acc = 0.f;
    #pragma unroll
    for (int i = 0; i < DD/2; ++i){
      float2 rv = *(const float2*)&row[2*i];
      u32 w = wreg[i];
      acc += rv.x * bf2f((u16)w);
      acc += rv.y * bf2f((u16)(w >> 16));
    }
    float sp = (j < BB) ? s1p[(size_t)j*DD + t] : s2p[(size_t)(j-BB)*DD + t];
    out[(size_t)j*DD + t] = 0.7f*sp + 0.3f*acc;
  }
}

extern "C" void kernel_launch(void* const* d_in, const int* in_sizes, int n_in,
                              void* d_out, int out_size, void* d_ws, size_t ws_size,
                              hipStream_t stream){
  const float* emb  = (const float*)d_in[0];
  const float* s1   = (const float*)d_in[1];
  const float* s2   = (const float*)d_in[2];
  const float* wp   = (const float*)d_in[3];
  const float* w1   = (const float*)d_in[4];
  const float* w2   = (const float*)d_in[5];
  const int* idx1 = (const int*)d_in[6];
  const int* idx2 = (const int*)d_in[7];
  const int* eidx = (const int*)d_in[8];
  const float* ew   = (const float*)d_in[9];
  const int* esrc = eidx;
  const int* edst = eidx + NE;

  char* ws = (char*)d_ws;
  size_t off = 0;
  auto A = [&](size_t b){ size_t r = off; off += (b + 255) & ~(size_t)255; return r; };
  float* dinv  = (float*)(ws + A((size_t)NN*4));
  int* owner   = (int*)  (ws + A((size_t)NN*4));
  int* slot1   = (int*)  (ws + A((size_t)NN*4));
  int* slotS   = (int*)  (ws + A((size_t)NN*4));
  int* list1   = (int*)  (ws + A((size_t)L1CAP*4));
  int* cnt     = (int*)  (ws + A(256));
  int* fc1     = (int*)  (ws + A(256*4));
  int* fcS     = (int*)  (ws + A(256*4));
  int* selCnt  = (int*)  (ws + A((size_t)GSC*4));
  int* selOff  = (int*)  (ws + A((size_t)(GSC+1)*4));
  int* l1Cnt   = (int*)  (ws + A((size_t)GSC*4));
  int* l1Off   = (int*)  (ws + A((size_t)(GSC+1)*4));
  int* cnt1    = (int*)  (ws + A((size_t)SCN*4));
  int* rowptr  = (int*)  (ws + A((size_t)(SCN+1)*4));
  int* rowptr2 = (int*)  (ws + A((size_t)2049*4));
  int* eS      = (int*)  (ws + A((size_t)ECAP*4));
  int* eD      = (int*)  (ws + A((size_t)ECAP*4));
  float* eWl   = (float*)(ws + A((size_t)ECAP*4));
  float* s1p   = (float*)(ws + A((size_t)BB*DD*4));
  float* s2p   = (float*)(ws + A((size_t)BB*DD*4));
  int* eL1s    = (int*)  (ws + A((size_t)L1ECAP*4));
  int* eL1c    = (int*)  (ws + A((size_t)L1ECAP*4));
  float* eL1w  = (float*)(ws + A((size_t)L1ECAP*4));
  // union1: slcA+slcB (dead after k_compact) overlaid by eCs/eCw/e2i/e2w
  size_t slcB1 = (size_t)GSC*CAPS*4;                 // 6.41 MB each
  size_t ovl   = (size_t)L1ECAP*4*2 + (size_t)ECAP*4*2; // 5.77 MB
  size_t u1 = 2*slcB1 > ovl ? 2*slcB1 : ovl;
  char* uni1 = ws + A(u1);
  int* slcA   = (int*)uni1;
  int* slcB   = (int*)(uni1 + slcB1);
  int* eCs    = (int*)uni1;
  float* eCw  = (float*)(uni1 + (size_t)L1ECAP*4);
  int* e2i    = (int*)(uni1 + (size_t)L1ECAP*8);
  float* e2w  = (float*)(uni1 + (size_t)L1ECAP*8 + (size_t)ECAP*4);
  // union2: partial (dead after k_dinv) / blk (cnt1..place) / agg1 (agg1..gemm1)
  size_t partB = (size_t)NCH*DEGB*CH*4;              // 19.2 MB
  size_t blkB  = (size_t)NSCH*PB*SLOTCH*4;           // 9.44 MB
  size_t aggB  = (size_t)L1CAP*DD*4;                 // 18.87 MB
  size_t u2 = partB; if (blkB > u2) u2 = blkB; if (aggB > u2) u2 = aggB;
  char* uni2 = ws + A(u2);
  float* partial = (float*)uni2;
  int* blk    = (int*)uni2;
  float* agg1 = (float*)uni2;
  u16*  hbuf  = (u16*) (ws + A((size_t)L1CAP*DD*2));
  float* agg2 = (float*)(ws + A((size_t)2*BB*DD*4));
  (void)in_sizes; (void)n_in; (void)out_size;
  if (ws_size < off) return;   // diagnostic: leaves out == 0 (absmax ~= 3.0)

  hipMemsetAsync(owner, 0xFF, (size_t)NN*4, stream);
  hipMemsetAsync(slot1, 0xFF, (size_t)NN*4, stream);
  hipMemsetAsync(slotS, 0xFF, (size_t)NN*4, stream);
  hipMemsetAsync(cnt,   0,    256, stream);
  hipMemsetAsync(cnt1,  0,    (size_t)SCN*4, stream);

  k_proj   <<<2*BB/PR, 128, 0, stream>>>(s1, s2, wp, s1p, s2p);
  k_mark   <<<8, 256, 0, stream>>>(idx1, idx2, owner, slot1, slotS);
  k_degp   <<<NCH*DEGB, 256, 0, stream>>>(edst, ew, partial);
  k_scansel<<<GSC, 256, 0, stream>>>(esrc, edst, slotS, slot1, selCnt, slcA);
  k_cflag  <<<256, 256, 0, stream>>>(slot1, slotS, fc1, fcS);
  k_asn    <<<256, 64, 0, stream>>>(fc1, fcS, slot1, slotS, list1, cnt);
  k_dinv   <<<(NN+255)/256, 256, 0, stream>>>(partial, dinv);
  k_scanl1 <<<GSC, 256, 0, stream>>>(edst, slot1, l1Cnt, slcB);
  k_escan2 <<<2, 1024, 0, stream>>>(selCnt, selOff, l1Cnt, l1Off, cnt);
  k_compact<<<2*GSC, 128, 0, stream>>>(slcA, slcB, selCnt, selOff, l1Cnt, l1Off,
                                       esrc, edst, ew, dinv, slot1,
                                       eS, eD, eWl, eL1s, eL1c, eL1w);
  k_cnt1   <<<NSCH*PB, 256, 0, stream>>>(eL1c, cnt, cnt1, blk);
  k_scanex <<<1, 1024, 0, stream>>>(cnt1, rowptr);
  k_off    <<<(SCN+255)/256, 256, 0, stream>>>(cnt, rowptr, blk);
  k_place  <<<NSCH*PB, 256, 0, stream>>>(eL1s, eL1c, eL1w, cnt, blk, eCs, eCw);
  k_agg1   <<<2048, 256, 0, stream>>>(rowptr, eCs, eCw, cnt, list1, dinv, owner, emb, s1p, s2p, agg1);
  k_gemm1  <<<2048, 128, 0, stream>>>(agg1, list1, cnt, w1, dinv, owner, emb, s1p, s2p, hbuf);
  k_csr2   <<<1, 1024, 0, stream>>>(eS, eD, eWl, cnt, slot1, slotS, dinv, rowptr2, e2i, e2w);
  k_agg2   <<<512, 256, 0, stream>>>(rowptr2, e2i, e2w, cnt, hbuf, agg2);
  k_final  <<<256, 128, 0, stream>>>(idx1, idx2, s1p, s2p, agg2, slot1, slotS, dinv, hbuf, w2, (float*)d_out);
}

// Round 9
// 469.983 us; speedup vs baseline: 1.3232x; 1.3232x over previous
//
#include <hip/hip_runtime.h>
#include <hip/hip_bf16.h>

#define NN 100000
#define NE 1600000
#define DD 128
#define SD 384
#define BB 1024
#define ECAP 65536
#define L1CAP 36864
#define L1ECAP 655360
#define NCH 8
#define CH  12500          // NCH*CH == NN
#define DEGB 48
#define ESH 33336          // mult of 8; DEGB*ESH >= NE
#define SLOTCH 12288
#define NSCH 3
#define PB 64
#define SCN (NSCH*SLOTCH)  // 36864
#define GSC 2048
#define CAPS 782           // ceil(NE/GSC)
#define CHN 391            // ceil(NN/256)
#define PR 8               // rows per k_proj block
#define PB2 64             // blocks for layer-2 CSR build

typedef unsigned int u32;
typedef unsigned short u16;
typedef unsigned long long u64;

__device__ __forceinline__ float bf2f(u16 x){ return __uint_as_float(((u32)x) << 16); }
__device__ __forceinline__ u16 f2bf(float f){
  u32 u = __float_as_uint(f);
  return (u16)((u + 0x7FFFu + ((u >> 16) & 1u)) >> 16);
}

// ---- s1p/s2p = s @ w_proj : 8-row blocked, transposed LDS -----------------
__global__ __launch_bounds__(128) void k_proj(const float* __restrict__ s1, const float* __restrict__ s2,
                                              const float* __restrict__ wp,
                                              float* __restrict__ s1p, float* __restrict__ s2p){
  __shared__ float srow[SD*10];
  int t = threadIdx.x;
  int row0 = blockIdx.x * PR;
  const float* sb = (row0 < BB) ? (s1 + (size_t)row0*SD) : (s2 + (size_t)(row0-BB)*SD);
  float* spb      = (row0 < BB) ? (s1p + (size_t)row0*DD) : (s2p + (size_t)(row0-BB)*DD);
  #pragma unroll
  for (int r = 0; r < PR; ++r)
    for (int k = t; k < SD; k += 128) srow[k*10 + r] = sb[r*SD + k];
  __syncthreads();
  float a0=0,a1=0,a2=0,a3=0,a4=0,a5=0,a6=0,a7=0;
  #pragma unroll 2
  for (int k = 0; k < SD; ++k){
    float w = wp[k*DD + t];
    float2 p0 = *(const float2*)&srow[k*10+0];
    float2 p1 = *(const float2*)&srow[k*10+2];
    float2 p2 = *(const float2*)&srow[k*10+4];
    float2 p3 = *(const float2*)&srow[k*10+6];
    a0 += p0.x*w; a1 += p0.y*w; a2 += p1.x*w; a3 += p1.y*w;
    a4 += p2.x*w; a5 += p2.y*w; a6 += p3.x*w; a7 += p3.y*w;
  }
  spb[0*DD+t]=a0; spb[1*DD+t]=a1; spb[2*DD+t]=a2; spb[3*DD+t]=a3;
  spb[4*DD+t]=a4; spb[5*DD+t]=a5; spb[6*DD+t]=a6; spb[7*DD+t]=a7;
}

// ---- flag S nodes + owner priority ----------------------------------------
__global__ void k_mark(const int* __restrict__ idx1, const int* __restrict__ idx2,
                       int* __restrict__ owner, int* __restrict__ slot1, int* __restrict__ slotS){
  int j = blockIdx.x*blockDim.x + threadIdx.x;
  if (j >= 2*BB) return;
  int n = (j < BB) ? idx1[j] : idx2[j - BB];
  atomicMax(&owner[n], j);
  slotS[n] = -2;
  slot1[n] = -2;
}

// ---- deg partial histograms: dense coalesced dump -------------------------
__global__ __launch_bounds__(256) void k_degp(const int* __restrict__ edst, const float* __restrict__ ew,
                                              float* __restrict__ partial){
  __shared__ float part[CH];
  int c  = blockIdx.x / DEGB;
  int r  = blockIdx.x % DEGB;
  int lo = c * CH;
  for (int i = threadIdx.x; i < CH; i += 256) part[i] = 0.f;
  __syncthreads();
  int e0 = r * ESH;
  int e1 = e0 + ESH; if (e1 > NE) e1 = NE;
  for (int e = e0 + threadIdx.x*4; e < e1; e += 256*4){
    int4   d4 = *(const int4*)(edst + e);
    float4 w4 = *(const float4*)(ew + e);
    unsigned q;
    q = (unsigned)(d4.x - lo); if (q < CH) atomicAdd(&part[q], w4.x);
    q = (unsigned)(d4.y - lo); if (q < CH) atomicAdd(&part[q], w4.y);
    q = (unsigned)(d4.z - lo); if (q < CH) atomicAdd(&part[q], w4.z);
    q = (unsigned)(d4.w - lo); if (q < CH) atomicAdd(&part[q], w4.w);
  }
  __syncthreads();
  float* dst = partial + ((size_t)(c*DEGB + r))*CH;
  for (int i = threadIdx.x; i < CH; i += 256) dst[i] = part[i];
}

// ---- dinv[n] = rsqrt(1 + sum_r partial[c][r][i]) --------------------------
__global__ __launch_bounds__(256) void k_dinv(const float* __restrict__ partial, float* __restrict__ dinv){
  int n = blockIdx.x*blockDim.x + threadIdx.x;
  if (n >= NN) return;
  int c = n / CH, i = n - c*CH;
  const float* p = partial + ((size_t)c*DEGB)*CH + i;
  float s = 0.f;
  #pragma unroll
  for (int r = 0; r < DEGB; ++r) s += p[(size_t)r*CH];
  dinv[n] = rsqrtf(s + 1.0f);
}

// ---- pass A: per-block-slice S-edge collection ----------------------------
__global__ __launch_bounds__(256) void k_scansel(const int* __restrict__ esrc, const int* __restrict__ edst,
    const int* __restrict__ slotS, int* __restrict__ slot1,
    int* __restrict__ selCnt, int* __restrict__ slcA){
  __shared__ int lcnt;
  __shared__ int buf[CAPS];
  int b = blockIdx.x, tid = threadIdx.x;
  if (tid == 0) lcnt = 0;
  __syncthreads();
  int lo = b*CAPS, hi = lo + CAPS; if (hi > NE) hi = NE;
  for (int e = lo + tid; e < hi; e += 256){
    int d = edst[e];
    if (slotS[d] != -1){
      int p = atomicAdd(&lcnt, 1);
      buf[p] = e;
      slot1[esrc[e]] = -2;
    }
  }
  __syncthreads();
  int c = lcnt;
  if (tid == 0) selCnt[b] = c;
  for (int i = tid; i < c; i += 256) slcA[lo + i] = buf[i];
}

// ---- pass B: per-block-slice L1-edge collection ---------------------------
__global__ __launch_bounds__(256) void k_scanl1(const int* __restrict__ edst, const int* __restrict__ slot1,
    int* __restrict__ l1Cnt, int* __restrict__ slcB){
  __shared__ int lcnt;
  __shared__ int buf[CAPS];
  int b = blockIdx.x, tid = threadIdx.x;
  if (tid == 0) lcnt = 0;
  __syncthreads();
  int lo = b*CAPS, hi = lo + CAPS; if (hi > NE) hi = NE;
  for (int e = lo + tid; e < hi; e += 256){
    if (slot1[edst[e]] >= 0){
      int p = atomicAdd(&lcnt, 1);
      buf[p] = e;
    }
  }
  __syncthreads();
  int c = lcnt;
  if (tid == 0) l1Cnt[b] = c;
  for (int i = tid; i < c; i += 256) slcB[lo + i] = buf[i];
}

// ---- count flags per node-chunk -------------------------------------------
__global__ __launch_bounds__(256) void k_cflag(const int* __restrict__ slot1, const int* __restrict__ slotS,
                                               int* __restrict__ fc1, int* __restrict__ fcS){
  __shared__ int r1[256], r2[256];
  int b = blockIdx.x;
  int lo = b*CHN, hi = lo + CHN; if (hi > NN) hi = NN;
  int c1 = 0, cS = 0;
  for (int n = lo + threadIdx.x; n < hi; n += 256){
    if (slot1[n] == -2) c1++;
    if (slotS[n] == -2) cS++;
  }
  r1[threadIdx.x] = c1; r2[threadIdx.x] = cS;
  __syncthreads();
  for (int s = 128; s > 0; s >>= 1){
    if (threadIdx.x < s){ r1[threadIdx.x] += r1[threadIdx.x+s]; r2[threadIdx.x] += r2[threadIdx.x+s]; }
    __syncthreads();
  }
  if (threadIdx.x == 0){ fc1[b] = r1[0]; fcS[b] = r2[0]; }
}

// ---- assign slots positionally --------------------------------------------
__global__ __launch_bounds__(64) void k_asn(const int* __restrict__ fc1, const int* __restrict__ fcS,
    int* __restrict__ slot1, int* __restrict__ slotS, int* __restrict__ list1, int* __restrict__ cnt){
  int b = blockIdx.x, lane = threadIdx.x;
  int s1 = 0, sS = 0;
  for (int q = lane; q < b; q += 64){ s1 += fc1[q]; sS += fcS[q]; }
  #pragma unroll
  for (int o = 1; o < 64; o <<= 1){ s1 += __shfl_xor(s1, o); sS += __shfl_xor(sS, o); }
  int base1 = s1, baseS = sS;
  int lo = b*CHN, hi = lo + CHN; if (hi > NN) hi = NN;
  for (int g = lo; g < hi; g += 64){
    int n = g + lane;
    bool f1 = (n < hi) && (slot1[n] == -2);
    bool fS = (n < hi) && (slotS[n] == -2);
    u64 m1 = __ballot(f1);
    u64 mS = __ballot(fS);
    if (f1){
      int sl = base1 + __popcll(m1 & ((1ull << lane) - 1ull));
      if (sl < L1CAP){ slot1[n] = sl; list1[sl] = n; } else slot1[n] = -3;
    }
    if (fS){
      int sl = baseS + __popcll(mS & ((1ull << lane) - 1ull));
      slotS[n] = (sl < 2*BB) ? sl : -3;
    }
    base1 += __popcll(m1);
    baseS += __popcll(mS);
  }
  if (b == 255 && lane == 0){ cnt[0] = base1; cnt[1] = baseS; }
}

// ---- two 2048-entry exclusive scans (grid = 2) ----------------------------
__global__ __launch_bounds__(1024) void k_escan2(const int* __restrict__ selCnt, int* __restrict__ selOff,
                                                 const int* __restrict__ l1Cnt, int* __restrict__ l1Off,
                                                 int* __restrict__ cnt){
  __shared__ int ts[1024];
  const int* in = (blockIdx.x == 0) ? selCnt : l1Cnt;
  int* out      = (blockIdx.x == 0) ? selOff : l1Off;
  int* cp       = cnt + (blockIdx.x == 0 ? 2 : 3);
  int tid = threadIdx.x;
  int a = in[2*tid], c = in[2*tid+1];
  int pair = a + c;
  ts[tid] = pair;
  __syncthreads();
  for (int o = 1; o < 1024; o <<= 1){
    int v = (tid >= o) ? ts[tid-o] : 0;
    __syncthreads();
    ts[tid] += v;
    __syncthreads();
  }
  int incl = ts[tid];
  int excl = incl - pair;
  out[2*tid]   = excl;
  out[2*tid+1] = excl + a;
  if (tid == 1023){ out[2048] = incl; *cp = incl; }
}

// ---- compact both slice lists (grid = 2*GSC) ------------------------------
__global__ __launch_bounds__(128) void k_compact(const int* __restrict__ slcA, const int* __restrict__ slcB,
    const int* __restrict__ selCnt, const int* __restrict__ selOff,
    const int* __restrict__ l1Cnt, const int* __restrict__ l1Off,
    const int* __restrict__ esrc, const int* __restrict__ edst, const float* __restrict__ ew,
    const float* __restrict__ dinv, const int* __restrict__ slot1,
    int* __restrict__ eS, int* __restrict__ eD, float* __restrict__ eWl,
    int* __restrict__ eL1s, int* __restrict__ eL1c, float* __restrict__ eL1w){
  int b = blockIdx.x;
  if (b < GSC){
    int cb = selCnt[b], off = selOff[b];
    for (int i = threadIdx.x; i < cb; i += 128){
      int o = off + i;
      if (o >= ECAP) break;
      int e = slcA[b*CAPS + i];
      eS[o] = esrc[e]; eD[o] = edst[e]; eWl[o] = ew[e];
    }
  } else {
    b -= GSC;
    int cb = l1Cnt[b], off = l1Off[b];
    for (int i = threadIdx.x; i < cb; i += 128){
      int o = off + i;
      if (o >= L1ECAP) break;
      int e = slcB[b*CAPS + i];
      int s = esrc[e];
      eL1s[o] = s;
      eL1c[o] = slot1[edst[e]];
      eL1w[o] = dinv[s]*ew[e];
    }
  }
}

// ---- per-block slot histograms (layer 1) ----------------------------------
__global__ __launch_bounds__(256) void k_cnt1(const int* __restrict__ eL1c, const int* __restrict__ cnt,
    int* __restrict__ cnt1, int* __restrict__ blk){
  __shared__ int hist[SLOTCH];
  int chunk = blockIdx.x / PB, b = blockIdx.x % PB;
  int n1 = cnt[0]; if (n1 > L1CAP) n1 = L1CAP;
  int lo = chunk * SLOTCH;
  if (lo >= n1) return;
  int m1 = cnt[3]; if (m1 > L1ECAP) m1 = L1ECAP;
  int slice = (m1 + PB - 1) / PB;
  int e0 = b*slice, e1 = e0 + slice; if (e1 > m1) e1 = m1;
  for (int i = threadIdx.x; i < SLOTCH; i += 256) hist[i] = 0;
  __syncthreads();
  for (int i = e0 + threadIdx.x; i < e1; i += 256){
    unsigned rel = (unsigned)(eL1c[i] - lo);
    if (rel < SLOTCH) atomicAdd(&hist[rel], 1);
  }
  __syncthreads();
  int* bc = blk + ((size_t)(chunk*PB + b))*SLOTCH;
  for (int i = threadIdx.x; i < SLOTCH; i += 256){
    int v = hist[i];
    bc[i] = v;
    if (v) atomicAdd(&cnt1[lo + i], v);
  }
}

// ---- exclusive scan over SCN counts ---------------------------------------
__global__ __launch_bounds__(1024) void k_scanex(const int* __restrict__ cnt1, int* __restrict__ rowptr){
  __shared__ int tsum[1024];
  int tid = threadIdx.x;
  int loc[36];
  int base = tid*36;
  int run = 0;
  #pragma unroll
  for (int k = 0; k < 36; ++k){ int v = cnt1[base+k]; loc[k] = run; run += v; }
  tsum[tid] = run;
  __syncthreads();
  for (int off = 1; off < 1024; off <<= 1){
    int v = (tid >= off) ? tsum[tid-off] : 0;
    __syncthreads();
    tsum[tid] += v;
    __syncthreads();
  }
  int inc = tsum[tid];
  int excl = inc - run;
  #pragma unroll
  for (int k = 0; k < 36; ++k) rowptr[base+k] = excl + loc[k];
  if (tid == 1023) rowptr[SCN] = inc;
}

// ---- per-(block,slot) start offsets (in place) ----------------------------
__global__ void k_off(const int* __restrict__ cnt, const int* __restrict__ rowptr, int* __restrict__ blk){
  int slot = blockIdx.x*blockDim.x + threadIdx.x;
  if (slot >= SCN) return;
  int n1 = cnt[0]; if (n1 > L1CAP) n1 = L1CAP;
  int chunk = slot / SLOTCH, rel = slot % SLOTCH;
  if (chunk*SLOTCH >= n1) return;
  int running = rowptr[slot];
  for (int b = 0; b < PB; ++b){
    size_t idx = ((size_t)(chunk*PB + b))*SLOTCH + rel;
    int t = blk[idx];
    blk[idx] = running;
    running += t;
  }
}

// ---- place edges into CSR (layer 1) ---------------------------------------
__global__ __launch_bounds__(256) void k_place(const int* __restrict__ eL1s, const int* __restrict__ eL1c,
    const float* __restrict__ eL1w, const int* __restrict__ cnt, const int* __restrict__ blk,
    int* __restrict__ eCs, float* __restrict__ eCw){
  __shared__ int cur[SLOTCH];
  int chunk = blockIdx.x / PB, b = blockIdx.x % PB;
  int n1 = cnt[0]; if (n1 > L1CAP) n1 = L1CAP;
  int lo = chunk * SLOTCH;
  if (lo >= n1) return;
  int m1 = cnt[3]; if (m1 > L1ECAP) m1 = L1ECAP;
  int slice = (m1 + PB - 1) / PB;
  int e0 = b*slice, e1 = e0 + slice; if (e1 > m1) e1 = m1;
  const int* bo = blk + ((size_t)(chunk*PB + b))*SLOTCH;
  for (int i = threadIdx.x; i < SLOTCH; i += 256) cur[i] = bo[i];
  __syncthreads();
  for (int i = e0 + threadIdx.x; i < e1; i += 256){
    int c = eL1c[i];
    unsigned rel = (unsigned)(c - lo);
    if (rel < SLOTCH){
      int pos = atomicAdd(&cur[rel], 1);
      eCs[pos] = eL1s[i];
      eCw[pos] = eL1w[i];
    }
  }
}

// ---- layer-1 aggregation, CSR owner-computes ------------------------------
__global__ __launch_bounds__(256) void k_agg1(const int* __restrict__ rowptr, const int* __restrict__ eCs,
    const float* __restrict__ eCw, const int* __restrict__ cnt, const int* __restrict__ list1,
    const float* __restrict__ dinv, const int* __restrict__ owner,
    const float* __restrict__ emb, const float* __restrict__ s1p, const float* __restrict__ s2p,
    float* __restrict__ agg1){
  int lane = threadIdx.x & 63;
  int wid  = (blockIdx.x*blockDim.x + threadIdx.x) >> 6;
  int nwv  = (gridDim.x*blockDim.x) >> 6;
  int n1 = cnt[0]; if (n1 > L1CAP) n1 = L1CAP;
  for (int c = wid; c < n1; c += nwv){
    int r0 = rowptr[c], r1 = rowptr[c+1];
    float ax = 0.f, ay = 0.f;
    for (int base = r0; base < r1; base += 64){
      int k = base + lane;
      bool valid = (k < r1);
      int   sv = valid ? eCs[k] : 0;
      float wv = valid ? eCw[k] : 0.f;
      int   ov = valid ? owner[sv] : 0;
      int m = r1 - base; if (m > 64) m = 64;
      for (int j = 0; j < m; ++j){
        int s    = __shfl(sv, j);
        float nw = __shfl(wv, j);
        int o    = __shfl(ov, j);
        const float* xp = (o < 0) ? (emb + (size_t)s*DD)
                        : (o < BB) ? (s1p + (size_t)o*DD) : (s2p + (size_t)(o-BB)*DD);
        float2 v = *(const float2*)(xp + lane*2);
        ax += nw*v.x; ay += nw*v.y;
      }
    }
    float dd = dinv[list1[c]];
    float2 res; res.x = ax*dd; res.y = ay*dd;
    *(float2*)(agg1 + (size_t)c*DD + lane*2) = res;
  }
}

// ---- h = relu((agg1 + self) @ w1), bf16 -----------------------------------
__global__ __launch_bounds__(128) void k_gemm1(const float* __restrict__ agg1, const int* __restrict__ list1,
    const int* __restrict__ cnt, const float* __restrict__ w1, const float* __restrict__ dinv,
    const int* __restrict__ owner, const float* __restrict__ emb,
    const float* __restrict__ s1p, const float* __restrict__ s2p,
    u16* __restrict__ hbuf){
  __shared__ float row[DD];
  int t = threadIdx.x;
  u32 wreg[DD/2];
  #pragma unroll
  for (int i = 0; i < DD/2; ++i){
    u32 lo = f2bf(w1[(2*i)*DD + t]);
    u32 hi = f2bf(w1[(2*i+1)*DD + t]);
    wreg[i] = lo | (hi << 16);
  }
  int n1 = cnt[0]; if (n1 > L1CAP) n1 = L1CAP;
  for (int sl = blockIdx.x; sl < n1; sl += gridDim.x){
    int n = list1[sl];
    int o = owner[n];
    float di = dinv[n];
    float xv;
    if (o < 0) xv = emb[(size_t)n*DD + t];
    else if (o < BB) xv = s1p[(size_t)o*DD + t];
    else xv = s2p[(size_t)(o-BB)*DD + t];
    __syncthreads();
    row[t] = agg1[(size_t)sl*DD + t] + di*di*xv;
    __syncthreads();
    float acc = 0.f;
    #pragma unroll
    for (int i = 0; i < DD/2; ++i){
      float2 rv = *(const float2*)&row[2*i];
      u32 w = wreg[i];
      acc += rv.x * bf2f((u16)w);
      acc += rv.y * bf2f((u16)(w >> 16));
    }
    hbuf[(size_t)sl*DD + t] = f2bf(fmaxf(acc, 0.f));
  }
}

// ---- layer-2 CSR: per-block histograms over 2048 S-slots ------------------
__global__ __launch_bounds__(256) void k_cnt2(const int* __restrict__ eD, const int* __restrict__ cnt,
    const int* __restrict__ slotS, int* __restrict__ blk2){
  __shared__ int hist[2*BB];
  int b = blockIdx.x, tid = threadIdx.x;
  int ne = cnt[2]; if (ne > ECAP) ne = ECAP;
  int slice = (ne + PB2 - 1) / PB2;
  int e0 = b*slice, e1 = e0 + slice; if (e1 > ne) e1 = ne;
  for (int i = tid; i < 2*BB; i += 256) hist[i] = 0;
  __syncthreads();
  for (int k = e0 + tid; k < e1; k += 256){
    int sd = slotS[eD[k]];
    if (sd >= 0) atomicAdd(&hist[sd], 1);
  }
  __syncthreads();
  int* dst = blk2 + (size_t)b*2*BB;
  for (int i = tid; i < 2*BB; i += 256) dst[i] = hist[i];
}

// ---- layer-2 CSR: totals + scan + per-block cursors (1 block) -------------
__global__ __launch_bounds__(1024) void k_scan2(int* __restrict__ blk2, int* __restrict__ rowptr2){
  __shared__ int ts[1024];
  int tid = threadIdx.x;
  int s0 = 2*tid, s1 = 2*tid+1;
  int a = 0, b = 0;
  for (int q = 0; q < PB2; ++q){ a += blk2[(size_t)q*2*BB + s0]; b += blk2[(size_t)q*2*BB + s1]; }
  int pair = a + b;
  ts[tid] = pair;
  __syncthreads();
  for (int o = 1; o < 1024; o <<= 1){
    int v = (tid >= o) ? ts[tid-o] : 0;
    __syncthreads();
    ts[tid] += v;
    __syncthreads();
  }
  int incl = ts[tid];
  int excl = incl - pair;
  rowptr2[s0] = excl;
  rowptr2[s1] = excl + a;
  if (tid == 1023) rowptr2[2*BB] = incl;
  int run0 = excl, run1 = excl + a;
  for (int q = 0; q < PB2; ++q){
    size_t i0 = (size_t)q*2*BB + s0, i1 = (size_t)q*2*BB + s1;
    int t0 = blk2[i0]; blk2[i0] = run0; run0 += t0;
    int t1 = blk2[i1]; blk2[i1] = run1; run1 += t1;
  }
}

// ---- layer-2 CSR: place with LDS cursors ----------------------------------
__global__ __launch_bounds__(256) void k_place2(const int* __restrict__ eS, const int* __restrict__ eD,
    const float* __restrict__ eWl, const int* __restrict__ cnt,
    const int* __restrict__ slot1, const int* __restrict__ slotS, const float* __restrict__ dinv,
    const int* __restrict__ blk2, int* __restrict__ e2i, float* __restrict__ e2w){
  __shared__ int cur[2*BB];
  int b = blockIdx.x, tid = threadIdx.x;
  int ne = cnt[2]; if (ne > ECAP) ne = ECAP;
  int slice = (ne + PB2 - 1) / PB2;
  int e0 = b*slice, e1 = e0 + slice; if (e1 > ne) e1 = ne;
  const int* src = blk2 + (size_t)b*2*BB;
  for (int i = tid; i < 2*BB; i += 256) cur[i] = src[i];
  __syncthreads();
  for (int k = e0 + tid; k < e1; k += 256){
    int d = eD[k];
    int sd = slotS[d];
    if (sd < 0) continue;
    int s = eS[k];
    int pos = atomicAdd(&cur[sd], 1);
    e2i[pos] = slot1[s];
    e2w[pos] = dinv[s]*dinv[d]*eWl[k];
  }
}

// ---- layer-2 aggregation, owner-computes ----------------------------------
__global__ __launch_bounds__(256) void k_agg2(const int* __restrict__ rowptr2, const int* __restrict__ e2i,
    const float* __restrict__ e2w, const int* __restrict__ cnt,
    const u16* __restrict__ hbuf, float* __restrict__ agg2){
  int lane = threadIdx.x & 63;
  int wid  = (blockIdx.x*blockDim.x + threadIdx.x) >> 6;
  int nwv  = (gridDim.x*blockDim.x) >> 6;
  int nS = cnt[1]; if (nS > 2*BB) nS = 2*BB;
  for (int c = wid; c < nS; c += nwv){
    int r0 = rowptr2[c], r1 = rowptr2[c+1];
    float ax = 0.f, ay = 0.f;
    for (int k = r0; k < r1; ++k){
      int i = e2i[k];
      if (i < 0) continue;
      float w = e2w[k];
      u32 p = *(const u32*)(hbuf + (size_t)i*DD + lane*2);
      ax += w*bf2f((u16)p);
      ay += w*bf2f((u16)(p >> 16));
    }
    float2 res; res.x = ax; res.y = ay;
    *(float2*)(agg2 + (size_t)c*DD + lane*2) = res;
  }
}

// ---- x_g = (agg2 + self) @ w2 ; out = 0.7*sp + 0.3*x_g --------------------
__global__ __launch_bounds__(128) void k_final(const int* __restrict__ idx1, const int* __restrict__ idx2,
    const float* __restrict__ s1p, const float* __restrict__ s2p,
    const float* __restrict__ agg2, const int* __restrict__ slot1, const int* __restrict__ slotS,
    const float* __restrict__ dinv, const u16* __restrict__ hbuf, const float* __restrict__ w2,
    float* __restrict__ out){
  __shared__ float row[DD];
  int t = threadIdx.x;
  u32 wreg[DD/2];
  #pragma unroll
  for (int i = 0; i < DD/2; ++i){
    u32 lo = f2bf(w2[(2*i)*DD + t]);
    u32 hi = f2bf(w2[(2*i+1)*DD + t]);
    wreg[i] = lo | (hi << 16);
  }
  for (int j = blockIdx.x; j < 2*BB; j += gridDim.x){
    int n = (j < BB) ? idx1[j] : idx2[j - BB];
    float di = dinv[n];
    int sl = slot1[n];
    float hv = (sl >= 0) ? bf2f(hbuf[(size_t)sl*DD + t]) : 0.f;
    __syncthreads();
    int ss = slotS[n];
    row[t] = (ss >= 0 ? agg2[(size_t)ss*DD + t] : 0.f) + di*di*hv;
    __syncthreads();
    float acc = 0.f;
    #pragma unroll
    for (int i = 0; i < DD/2; ++i){
      float2 rv = *(const float2*)&row[2*i];
      u32 w = wreg[i];
      acc += rv.x * bf2f((u16)w);
      acc += rv.y * bf2f((u16)(w >> 16));
    }
    float sp = (j < BB) ? s1p[(size_t)j*DD + t] : s2p[(size_t)(j-BB)*DD + t];
    out[(size_t)j*DD + t] = 0.7f*sp + 0.3f*acc;
  }
}

extern "C" void kernel_launch(void* const* d_in, const int* in_sizes, int n_in,
                              void* d_out, int out_size, void* d_ws, size_t ws_size,
                              hipStream_t stream){
  const float* emb  = (const float*)d_in[0];
  const float* s1   = (const float*)d_in[1];
  const float* s2   = (const float*)d_in[2];
  const float* wp   = (const float*)d_in[3];
  const float* w1   = (const float*)d_in[4];
  const float* w2   = (const float*)d_in[5];
  const int* idx1 = (const int*)d_in[6];
  const int* idx2 = (const int*)d_in[7];
  const int* eidx = (const int*)d_in[8];
  const float* ew   = (const float*)d_in[9];
  const int* esrc = eidx;
  const int* edst = eidx + NE;

  char* ws = (char*)d_ws;
  size_t off = 0;
  auto A = [&](size_t b){ size_t r = off; off += (b + 255) & ~(size_t)255; return r; };
  float* dinv  = (float*)(ws + A((size_t)NN*4));
  int* owner   = (int*)  (ws + A((size_t)NN*4));
  int* slot1   = (int*)  (ws + A((size_t)NN*4));
  int* slotS   = (int*)  (ws + A((size_t)NN*4));
  int* list1   = (int*)  (ws + A((size_t)L1CAP*4));
  int* cnt     = (int*)  (ws + A(256));
  int* fc1     = (int*)  (ws + A(256*4));
  int* fcS     = (int*)  (ws + A(256*4));
  int* selCnt  = (int*)  (ws + A((size_t)GSC*4));
  int* selOff  = (int*)  (ws + A((size_t)(GSC+1)*4));
  int* l1Cnt   = (int*)  (ws + A((size_t)GSC*4));
  int* l1Off   = (int*)  (ws + A((size_t)(GSC+1)*4));
  int* cnt1    = (int*)  (ws + A((size_t)SCN*4));
  int* rowptr  = (int*)  (ws + A((size_t)(SCN+1)*4));
  int* rowptr2 = (int*)  (ws + A((size_t)(2*BB+1)*4));
  int* blk2    = (int*)  (ws + A((size_t)PB2*2*BB*4));
  int* eS      = (int*)  (ws + A((size_t)ECAP*4));
  int* eD      = (int*)  (ws + A((size_t)ECAP*4));
  float* eWl   = (float*)(ws + A((size_t)ECAP*4));
  float* s1p   = (float*)(ws + A((size_t)BB*DD*4));
  float* s2p   = (float*)(ws + A((size_t)BB*DD*4));
  int* eL1s    = (int*)  (ws + A((size_t)L1ECAP*4));
  int* eL1c    = (int*)  (ws + A((size_t)L1ECAP*4));
  float* eL1w  = (float*)(ws + A((size_t)L1ECAP*4));
  // union1: slcA+slcB (dead after k_compact) overlaid by eCs/eCw/e2i/e2w
  size_t slcB1 = (size_t)GSC*CAPS*4;
  size_t ovl   = (size_t)L1ECAP*4*2 + (size_t)ECAP*4*2;
  size_t u1 = 2*slcB1 > ovl ? 2*slcB1 : ovl;
  char* uni1 = ws + A(u1);
  int* slcA   = (int*)uni1;
  int* slcB   = (int*)(uni1 + slcB1);
  int* eCs    = (int*)uni1;
  float* eCw  = (float*)(uni1 + (size_t)L1ECAP*4);
  int* e2i    = (int*)(uni1 + (size_t)L1ECAP*8);
  float* e2w  = (float*)(uni1 + (size_t)L1ECAP*8 + (size_t)ECAP*4);
  // union2: partial (dead after k_dinv) / blk (cnt1..place) / agg1 (agg1..gemm1)
  size_t partB = (size_t)NCH*DEGB*CH*4;
  size_t blkB  = (size_t)NSCH*PB*SLOTCH*4;
  size_t aggB  = (size_t)L1CAP*DD*4;
  size_t u2 = partB; if (blkB > u2) u2 = blkB; if (aggB > u2) u2 = aggB;
  char* uni2 = ws + A(u2);
  float* partial = (float*)uni2;
  int* blk    = (int*)uni2;
  float* agg1 = (float*)uni2;
  u16*  hbuf  = (u16*) (ws + A((size_t)L1CAP*DD*2));
  float* agg2 = (float*)(ws + A((size_t)2*BB*DD*4));
  (void)in_sizes; (void)n_in; (void)out_size;
  if (ws_size < off) return;   // diagnostic: leaves out == 0 (absmax ~= 3.0)

  hipMemsetAsync(owner, 0xFF, (size_t)NN*4, stream);
  hipMemsetAsync(slot1, 0xFF, (size_t)NN*4, stream);
  hipMemsetAsync(slotS, 0xFF, (size_t)NN*4, stream);
  hipMemsetAsync(cnt,   0,    256, stream);
  hipMemsetAsync(cnt1,  0,    (size_t)SCN*4, stream);

  k_proj   <<<2*BB/PR, 128, 0, stream>>>(s1, s2, wp, s1p, s2p);
  k_mark   <<<8, 256, 0, stream>>>(idx1, idx2, owner, slot1, slotS);
  k_degp   <<<NCH*DEGB, 256, 0, stream>>>(edst, ew, partial);
  k_scansel<<<GSC, 256, 0, stream>>>(esrc, edst, slotS, slot1, selCnt, slcA);
  k_cflag  <<<256, 256, 0, stream>>>(slot1, slotS, fc1, fcS);
  k_asn    <<<256, 64, 0, stream>>>(fc1, fcS, slot1, slotS, list1, cnt);
  k_dinv   <<<(NN+255)/256, 256, 0, stream>>>(partial, dinv);
  k_scanl1 <<<GSC, 256, 0, stream>>>(edst, slot1, l1Cnt, slcB);
  k_escan2 <<<2, 1024, 0, stream>>>(selCnt, selOff, l1Cnt, l1Off, cnt);
  k_compact<<<2*GSC, 128, 0, stream>>>(slcA, slcB, selCnt, selOff, l1Cnt, l1Off,
                                       esrc, edst, ew, dinv, slot1,
                                       eS, eD, eWl, eL1s, eL1c, eL1w);
  k_cnt1   <<<NSCH*PB, 256, 0, stream>>>(eL1c, cnt, cnt1, blk);
  k_scanex <<<1, 1024, 0, stream>>>(cnt1, rowptr);
  k_off    <<<(SCN+255)/256, 256, 0, stream>>>(cnt, rowptr, blk);
  k_place  <<<NSCH*PB, 256, 0, stream>>>(eL1s, eL1c, eL1w, cnt, blk, eCs, eCw);
  k_agg1   <<<2048, 256, 0, stream>>>(rowptr, eCs, eCw, cnt, list1, dinv, owner, emb, s1p, s2p, agg1);
  k_gemm1  <<<2048, 128, 0, stream>>>(agg1, list1, cnt, w1, dinv, owner, emb, s1p, s2p, hbuf);
  k_cnt2   <<<PB2, 256, 0, stream>>>(eD, cnt, slotS, blk2);
  k_scan2  <<<1, 1024, 0, stream>>>(blk2, rowptr2);
  k_place2 <<<PB2, 256, 0, stream>>>(eS, eD, eWl, cnt, slot1, slotS, dinv, blk2, e2i, e2w);
  k_agg2   <<<512, 256, 0, stream>>>(rowptr2, e2i, e2w, cnt, hbuf, agg2);
  k_final  <<<256, 128, 0, stream>>>(idx1, idx2, s1p, s2p, agg2, slot1, slotS, dinv, hbuf, w2, (float*)d_out);
}

// Round 11
// 430.108 us; speedup vs baseline: 1.4459x; 1.0927x over previous
//
#include <hip/hip_runtime.h>
#include <hip/hip_bf16.h>

#define NN 100000
#define NE 1600000
#define DD 128
#define SD 384
#define BB 1024
#define ECAP 65536
#define L1CAP 36864
#define L1ECAP 655360
#define NCH 8
#define CH  12500          // NCH*CH == NN
#define DEGB 48
#define ESH 33336          // mult of 8; DEGB*ESH >= NE
#define SLOTCH 12288
#define NSCH 3
#define PB 64
#define SCN (NSCH*SLOTCH)  // 36864
#define GSC 2048
#define CAPS 782           // ceil(NE/GSC)
#define CHN 391            // ceil(NN/256)
#define PR 8               // rows per k_projp block
#define KS 4               // K-split segments (SD/KS = 96)
#define KSEG (SD/KS)
#define PB2 64             // blocks for layer-2 CSR build

typedef unsigned int u32;
typedef unsigned short u16;
typedef unsigned long long u64;

__device__ __forceinline__ float bf2f(u16 x){ return __uint_as_float(((u32)x) << 16); }
__device__ __forceinline__ u16 f2bf(float f){
  u32 u = __float_as_uint(f);
  return (u16)((u + 0x7FFFu + ((u >> 16) & 1u)) >> 16);
}

// ---- proj partials: 8 rows × 96-K per block, 4 blocks/CU ------------------
__global__ __launch_bounds__(128) void k_projp(const float* __restrict__ s1, const float* __restrict__ s2,
                                               const float* __restrict__ wp, float* __restrict__ pp){
  __shared__ float srow[KSEG*10];
  int t = threadIdx.x;
  int rowgrp = blockIdx.x / KS;
  int ks     = blockIdx.x % KS;
  int row0 = rowgrp * PR;
  int k0 = ks * KSEG;
  const float* sb = (row0 < BB) ? (s1 + (size_t)row0*SD) : (s2 + (size_t)(row0-BB)*SD);
  #pragma unroll
  for (int r = 0; r < PR; ++r)
    for (int k = t; k < KSEG; k += 128) srow[k*10 + r] = sb[r*SD + k0 + k];
  __syncthreads();
  float a0=0,a1=0,a2=0,a3=0,a4=0,a5=0,a6=0,a7=0;
  #pragma unroll 4
  for (int k = 0; k < KSEG; ++k){
    float w = wp[(k0 + k)*DD + t];
    float2 p0 = *(const float2*)&srow[k*10+0];
    float2 p1 = *(const float2*)&srow[k*10+2];
    float2 p2 = *(const float2*)&srow[k*10+4];
    float2 p3 = *(const float2*)&srow[k*10+6];
    a0 += p0.x*w; a1 += p0.y*w; a2 += p1.x*w; a3 += p1.y*w;
    a4 += p2.x*w; a5 += p2.y*w; a6 += p3.x*w; a7 += p3.y*w;
  }
  float* d = pp + ((size_t)ks*2*BB + row0)*DD + t;
  d[0*DD]=a0; d[1*DD]=a1; d[2*DD]=a2; d[3*DD]=a3;
  d[4*DD]=a4; d[5*DD]=a5; d[6*DD]=a6; d[7*DD]=a7;
}

// ---- reduce K-split partials → s1p/s2p ------------------------------------
__global__ __launch_bounds__(256) void k_projr(const float* __restrict__ pp,
                                               float* __restrict__ s1p, float* __restrict__ s2p){
  int idx = blockIdx.x*256 + threadIdx.x;          // 0 .. 2*BB*DD-1
  float s = 0.f;
  #pragma unroll
  for (int ks = 0; ks < KS; ++ks) s += pp[(size_t)ks*2*BB*DD + idx];
  int row = idx >> 7;
  int t   = idx & (DD-1);
  if (row < BB) s1p[(size_t)row*DD + t] = s;
  else          s2p[(size_t)(row-BB)*DD + t] = s;
}

// ---- flag S nodes + owner priority ----------------------------------------
__global__ void k_mark(const int* __restrict__ idx1, const int* __restrict__ idx2,
                       int* __restrict__ owner, int* __restrict__ slot1, int* __restrict__ slotS){
  int j = blockIdx.x*blockDim.x + threadIdx.x;
  if (j >= 2*BB) return;
  int n = (j < BB) ? idx1[j] : idx2[j - BB];
  atomicMax(&owner[n], j);
  slotS[n] = -2;
  slot1[n] = -2;
}

// ---- deg partial histograms: dense coalesced dump -------------------------
__global__ __launch_bounds__(256) void k_degp(const int* __restrict__ edst, const float* __restrict__ ew,
                                              float* __restrict__ partial){
  __shared__ float part[CH];
  int c  = blockIdx.x / DEGB;
  int r  = blockIdx.x % DEGB;
  int lo = c * CH;
  for (int i = threadIdx.x; i < CH; i += 256) part[i] = 0.f;
  __syncthreads();
  int e0 = r * ESH;
  int e1 = e0 + ESH; if (e1 > NE) e1 = NE;
  for (int e = e0 + threadIdx.x*4; e < e1; e += 256*4){
    int4   d4 = *(const int4*)(edst + e);
    float4 w4 = *(const float4*)(ew + e);
    unsigned q;
    q = (unsigned)(d4.x - lo); if (q < CH) atomicAdd(&part[q], w4.x);
    q = (unsigned)(d4.y - lo); if (q < CH) atomicAdd(&part[q], w4.y);
    q = (unsigned)(d4.z - lo); if (q < CH) atomicAdd(&part[q], w4.z);
    q = (unsigned)(d4.w - lo); if (q < CH) atomicAdd(&part[q], w4.w);
  }
  __syncthreads();
  float* dst = partial + ((size_t)(c*DEGB + r))*CH;
  for (int i = threadIdx.x; i < CH; i += 256) dst[i] = part[i];
}

// ---- dinv[n] = rsqrt(1 + sum_r partial[c][r][i]) --------------------------
__global__ __launch_bounds__(256) void k_dinv(const float* __restrict__ partial, float* __restrict__ dinv){
  int n = blockIdx.x*blockDim.x + threadIdx.x;
  if (n >= NN) return;
  int c = n / CH, i = n - c*CH;
  const float* p = partial + ((size_t)c*DEGB)*CH + i;
  float s = 0.f;
  #pragma unroll
  for (int r = 0; r < DEGB; ++r) s += p[(size_t)r*CH];
  dinv[n] = rsqrtf(s + 1.0f);
}

// ---- pass A: per-block-slice S-edge collection ----------------------------
__global__ __launch_bounds__(256) void k_scansel(const int* __restrict__ esrc, const int* __restrict__ edst,
    const int* __restrict__ slotS, int* __restrict__ slot1,
    int* __restrict__ selCnt, int* __restrict__ slcA){
  __shared__ int lcnt;
  __shared__ int buf[CAPS];
  int b = blockIdx.x, tid = threadIdx.x;
  if (tid == 0) lcnt = 0;
  __syncthreads();
  int lo = b*CAPS, hi = lo + CAPS; if (hi > NE) hi = NE;
  for (int e = lo + tid; e < hi; e += 256){
    int d = edst[e];
    if (slotS[d] != -1){
      int p = atomicAdd(&lcnt, 1);
      buf[p] = e;
      slot1[esrc[e]] = -2;
    }
  }
  __syncthreads();
  int c = lcnt;
  if (tid == 0) selCnt[b] = c;
  for (int i = tid; i < c; i += 256) slcA[lo + i] = buf[i];
}

// ---- pass B: per-block-slice L1-edge collection ---------------------------
__global__ __launch_bounds__(256) void k_scanl1(const int* __restrict__ edst, const int* __restrict__ slot1,
    int* __restrict__ l1Cnt, int* __restrict__ slcB){
  __shared__ int lcnt;
  __shared__ int buf[CAPS];
  int b = blockIdx.x, tid = threadIdx.x;
  if (tid == 0) lcnt = 0;
  __syncthreads();
  int lo = b*CAPS, hi = lo + CAPS; if (hi > NE) hi = NE;
  for (int e = lo + tid; e < hi; e += 256){
    if (slot1[edst[e]] >= 0){
      int p = atomicAdd(&lcnt, 1);
      buf[p] = e;
    }
  }
  __syncthreads();
  int c = lcnt;
  if (tid == 0) l1Cnt[b] = c;
  for (int i = tid; i < c; i += 256) slcB[lo + i] = buf[i];
}

// ---- count flags per node-chunk -------------------------------------------
__global__ __launch_bounds__(256) void k_cflag(const int* __restrict__ slot1, const int* __restrict__ slotS,
                                               int* __restrict__ fc1, int* __restrict__ fcS){
  __shared__ int r1[256], r2[256];
  int b = blockIdx.x;
  int lo = b*CHN, hi = lo + CHN; if (hi > NN) hi = NN;
  int c1 = 0, cS = 0;
  for (int n = lo + threadIdx.x; n < hi; n += 256){
    if (slot1[n] == -2) c1++;
    if (slotS[n] == -2) cS++;
  }
  r1[threadIdx.x] = c1; r2[threadIdx.x] = cS;
  __syncthreads();
  for (int s = 128; s > 0; s >>= 1){
    if (threadIdx.x < s){ r1[threadIdx.x] += r1[threadIdx.x+s]; r2[threadIdx.x] += r2[threadIdx.x+s]; }
    __syncthreads();
  }
  if (threadIdx.x == 0){ fc1[b] = r1[0]; fcS[b] = r2[0]; }
}

// ---- assign slots positionally --------------------------------------------
__global__ __launch_bounds__(64) void k_asn(const int* __restrict__ fc1, const int* __restrict__ fcS,
    int* __restrict__ slot1, int* __restrict__ slotS, int* __restrict__ list1, int* __restrict__ cnt){
  int b = blockIdx.x, lane = threadIdx.x;
  int s1 = 0, sS = 0;
  for (int q = lane; q < b; q += 64){ s1 += fc1[q]; sS += fcS[q]; }
  #pragma unroll
  for (int o = 1; o < 64; o <<= 1){ s1 += __shfl_xor(s1, o); sS += __shfl_xor(sS, o); }
  int base1 = s1, baseS = sS;
  int lo = b*CHN, hi = lo + CHN; if (hi > NN) hi = NN;
  for (int g = lo; g < hi; g += 64){
    int n = g + lane;
    bool f1 = (n < hi) && (slot1[n] == -2);
    bool fS = (n < hi) && (slotS[n] == -2);
    u64 m1 = __ballot(f1);
    u64 mS = __ballot(fS);
    if (f1){
      int sl = base1 + __popcll(m1 & ((1ull << lane) - 1ull));
      if (sl < L1CAP){ slot1[n] = sl; list1[sl] = n; } else slot1[n] = -3;
    }
    if (fS){
      int sl = baseS + __popcll(mS & ((1ull << lane) - 1ull));
      slotS[n] = (sl < 2*BB) ? sl : -3;
    }
    base1 += __popcll(m1);
    baseS += __popcll(mS);
  }
  if (b == 255 && lane == 0){ cnt[0] = base1; cnt[1] = baseS; }
}

// ---- two 2048-entry exclusive scans (grid = 2) ----------------------------
__global__ __launch_bounds__(1024) void k_escan2(const int* __restrict__ selCnt, int* __restrict__ selOff,
                                                 const int* __restrict__ l1Cnt, int* __restrict__ l1Off,
                                                 int* __restrict__ cnt){
  __shared__ int ts[1024];
  const int* in = (blockIdx.x == 0) ? selCnt : l1Cnt;
  int* out      = (blockIdx.x == 0) ? selOff : l1Off;
  int* cp       = cnt + (blockIdx.x == 0 ? 2 : 3);
  int tid = threadIdx.x;
  int a = in[2*tid], c = in[2*tid+1];
  int pair = a + c;
  ts[tid] = pair;
  __syncthreads();
  for (int o = 1; o < 1024; o <<= 1){
    int v = (tid >= o) ? ts[tid-o] : 0;
    __syncthreads();
    ts[tid] += v;
    __syncthreads();
  }
  int incl = ts[tid];
  int excl = incl - pair;
  out[2*tid]   = excl;
  out[2*tid+1] = excl + a;
  if (tid == 1023){ out[2048] = incl; *cp = incl; }
}

// ---- compact both slice lists (grid = 2*GSC) ------------------------------
__global__ __launch_bounds__(128) void k_compact(const int* __restrict__ slcA, const int* __restrict__ slcB,
    const int* __restrict__ selCnt, const int* __restrict__ selOff,
    const int* __restrict__ l1Cnt, const int* __restrict__ l1Off,
    const int* __restrict__ esrc, const int* __restrict__ edst, const float* __restrict__ ew,
    const float* __restrict__ dinv, const int* __restrict__ slot1,
    int* __restrict__ eS, int* __restrict__ eD, float* __restrict__ eWl,
    int* __restrict__ eL1s, int* __restrict__ eL1c, float* __restrict__ eL1w){
  int b = blockIdx.x;
  if (b < GSC){
    int cb = selCnt[b], off = selOff[b];
    for (int i = threadIdx.x; i < cb; i += 128){
      int o = off + i;
      if (o >= ECAP) break;
      int e = slcA[b*CAPS + i];
      eS[o] = esrc[e]; eD[o] = edst[e]; eWl[o] = ew[e];
    }
  } else {
    b -= GSC;
    int cb = l1Cnt[b], off = l1Off[b];
    for (int i = threadIdx.x; i < cb; i += 128){
      int o = off + i;
      if (o >= L1ECAP) break;
      int e = slcB[b*CAPS + i];
      int s = esrc[e];
      eL1s[o] = s;
      eL1c[o] = slot1[edst[e]];
      eL1w[o] = dinv[s]*ew[e];
    }
  }
}

// ---- per-block slot histograms (layer 1) ----------------------------------
__global__ __launch_bounds__(256) void k_cnt1(const int* __restrict__ eL1c, const int* __restrict__ cnt,
    int* __restrict__ cnt1, int* __restrict__ blk){
  __shared__ int hist[SLOTCH];
  int chunk = blockIdx.x / PB, b = blockIdx.x % PB;
  int n1 = cnt[0]; if (n1 > L1CAP) n1 = L1CAP;
  int lo = chunk * SLOTCH;
  if (lo >= n1) return;
  int m1 = cnt[3]; if (m1 > L1ECAP) m1 = L1ECAP;
  int slice = (m1 + PB - 1) / PB;
  int e0 = b*slice, e1 = e0 + slice; if (e1 > m1) e1 = m1;
  for (int i = threadIdx.x; i < SLOTCH; i += 256) hist[i] = 0;
  __syncthreads();
  for (int i = e0 + threadIdx.x; i < e1; i += 256){
    unsigned rel = (unsigned)(eL1c[i] - lo);
    if (rel < SLOTCH) atomicAdd(&hist[rel], 1);
  }
  __syncthreads();
  int* bc = blk + ((size_t)(chunk*PB + b))*SLOTCH;
  for (int i = threadIdx.x; i < SLOTCH; i += 256){
    int v = hist[i];
    bc[i] = v;
    if (v) atomicAdd(&cnt1[lo + i], v);
  }
}

// ---- exclusive scan over SCN counts ---------------------------------------
__global__ __launch_bounds__(1024) void k_scanex(const int* __restrict__ cnt1, int* __restrict__ rowptr){
  __shared__ int tsum[1024];
  int tid = threadIdx.x;
  int loc[36];
  int base = tid*36;
  int run = 0;
  #pragma unroll
  for (int k = 0; k < 36; ++k){ int v = cnt1[base+k]; loc[k] = run; run += v; }
  tsum[tid] = run;
  __syncthreads();
  for (int off = 1; off < 1024; off <<= 1){
    int v = (tid >= off) ? tsum[tid-off] : 0;
    __syncthreads();
    tsum[tid] += v;
    __syncthreads();
  }
  int inc = tsum[tid];
  int excl = inc - run;
  #pragma unroll
  for (int k = 0; k < 36; ++k) rowptr[base+k] = excl + loc[k];
  if (tid == 1023) rowptr[SCN] = inc;
}

// ---- per-(block,slot) start offsets (in place) ----------------------------
__global__ void k_off(const int* __restrict__ cnt, const int* __restrict__ rowptr, int* __restrict__ blk){
  int slot = blockIdx.x*blockDim.x + threadIdx.x;
  if (slot >= SCN) return;
  int n1 = cnt[0]; if (n1 > L1CAP) n1 = L1CAP;
  int chunk = slot / SLOTCH, rel = slot % SLOTCH;
  if (chunk*SLOTCH >= n1) return;
  int running = rowptr[slot];
  for (int b = 0; b < PB; ++b){
    size_t idx = ((size_t)(chunk*PB + b))*SLOTCH + rel;
    int t = blk[idx];
    blk[idx] = running;
    running += t;
  }
}

// ---- place edges into CSR (layer 1) ---------------------------------------
__global__ __launch_bounds__(256) void k_place(const int* __restrict__ eL1s, const int* __restrict__ eL1c,
    const float* __restrict__ eL1w, const int* __restrict__ cnt, const int* __restrict__ blk,
    int* __restrict__ eCs, float* __restrict__ eCw){
  __shared__ int cur[SLOTCH];
  int chunk = blockIdx.x / PB, b = blockIdx.x % PB;
  int n1 = cnt[0]; if (n1 > L1CAP) n1 = L1CAP;
  int lo = chunk * SLOTCH;
  if (lo >= n1) return;
  int m1 = cnt[3]; if (m1 > L1ECAP) m1 = L1ECAP;
  int slice = (m1 + PB - 1) / PB;
  int e0 = b*slice, e1 = e0 + slice; if (e1 > m1) e1 = m1;
  const int* bo = blk + ((size_t)(chunk*PB + b))*SLOTCH;
  for (int i = threadIdx.x; i < SLOTCH; i += 256) cur[i] = bo[i];
  __syncthreads();
  for (int i = e0 + threadIdx.x; i < e1; i += 256){
    int c = eL1c[i];
    unsigned rel = (unsigned)(c - lo);
    if (rel < SLOTCH){
      int pos = atomicAdd(&cur[rel], 1);
      eCs[pos] = eL1s[i];
      eCw[pos] = eL1w[i];
    }
  }
}

// ---- layer-1 aggregation, CSR owner-computes ------------------------------
__global__ __launch_bounds__(256) void k_agg1(const int* __restrict__ rowptr, const int* __restrict__ eCs,
    const float* __restrict__ eCw, const int* __restrict__ cnt, const int* __restrict__ list1,
    const float* __restrict__ dinv, const int* __restrict__ owner,
    const float* __restrict__ emb, const float* __restrict__ s1p, const float* __restrict__ s2p,
    float* __restrict__ agg1){
  int lane = threadIdx.x & 63;
  int wid  = (blockIdx.x*blockDim.x + threadIdx.x) >> 6;
  int nwv  = (gridDim.x*blockDim.x) >> 6;
  int n1 = cnt[0]; if (n1 > L1CAP) n1 = L1CAP;
  for (int c = wid; c < n1; c += nwv){
    int r0 = rowptr[c], r1 = rowptr[c+1];
    float ax = 0.f, ay = 0.f;
    for (int base = r0; base < r1; base += 64){
      int k = base + lane;
      bool valid = (k < r1);
      int   sv = valid ? eCs[k] : 0;
      float wv = valid ? eCw[k] : 0.f;
      int   ov = valid ? owner[sv] : 0;
      int m = r1 - base; if (m > 64) m = 64;
      for (int j = 0; j < m; ++j){
        int s    = __shfl(sv, j);
        float nw = __shfl(wv, j);
        int o    = __shfl(ov, j);
        const float* xp = (o < 0) ? (emb + (size_t)s*DD)
                        : (o < BB) ? (s1p + (size_t)o*DD) : (s2p + (size_t)(o-BB)*DD);
        float2 v = *(const float2*)(xp + lane*2);
        ax += nw*v.x; ay += nw*v.y;
      }
    }
    float dd = dinv[list1[c]];
    float2 res; res.x = ax*dd; res.y = ay*dd;
    *(float2*)(agg1 + (size_t)c*DD + lane*2) = res;
  }
}

// ---- h = relu((agg1 + self) @ w1), bf16 -----------------------------------
__global__ __launch_bounds__(128) void k_gemm1(const float* __restrict__ agg1, const int* __restrict__ list1,
    const int* __restrict__ cnt, const float* __restrict__ w1, const float* __restrict__ dinv,
    const int* __restrict__ owner, const float* __restrict__ emb,
    const float* __restrict__ s1p, const float* __restrict__ s2p,
    u16* __restrict__ hbuf){
  __shared__ float row[DD];
  int t = threadIdx.x;
  u32 wreg[DD/2];
  #pragma unroll
  for (int i = 0; i < DD/2; ++i){
    u32 lo = f2bf(w1[(2*i)*DD + t]);
    u32 hi = f2bf(w1[(2*i+1)*DD + t]);
    wreg[i] = lo | (hi << 16);
  }
  int n1 = cnt[0]; if (n1 > L1CAP) n1 = L1CAP;
  for (int sl = blockIdx.x; sl < n1; sl += gridDim.x){
    int n = list1[sl];
    int o = owner[n];
    float di = dinv[n];
    float xv;
    if (o < 0) xv = emb[(size_t)n*DD + t];
    else if (o < BB) xv = s1p[(size_t)o*DD + t];
    else xv = s2p[(size_t)(o-BB)*DD + t];
    __syncthreads();
    row[t] = agg1[(size_t)sl*DD + t] + di*di*xv;
    __syncthreads();
    float acc = 0.f;
    #pragma unroll
    for (int i = 0; i < DD/2; ++i){
      float2 rv = *(const float2*)&row[2*i];
      u32 w = wreg[i];
      acc += rv.x * bf2f((u16)w);
      acc += rv.y * bf2f((u16)(w >> 16));
    }
    hbuf[(size_t)sl*DD + t] = f2bf(fmaxf(acc, 0.f));
  }
}

// ---- layer-2 CSR: per-block histograms over 2048 S-slots ------------------
__global__ __launch_bounds__(256) void k_cnt2(const int* __restrict__ eD, const int* __restrict__ cnt,
    const int* __restrict__ slotS, int* __restrict__ blk2){
  __shared__ int hist[2*BB];
  int b = blockIdx.x, tid = threadIdx.x;
  int ne = cnt[2]; if (ne > ECAP) ne = ECAP;
  int slice = (ne + PB2 - 1) / PB2;
  int e0 = b*slice, e1 = e0 + slice; if (e1 > ne) e1 = ne;
  for (int i = tid; i < 2*BB; i += 256) hist[i] = 0;
  __syncthreads();
  for (int k = e0 + tid; k < e1; k += 256){
    int sd = slotS[eD[k]];
    if (sd >= 0) atomicAdd(&hist[sd], 1);
  }
  __syncthreads();
  int* dst = blk2 + (size_t)b*2*BB;
  for (int i = tid; i < 2*BB; i += 256) dst[i] = hist[i];
}

// ---- layer-2 CSR: totals + scan + per-block cursors (1 block) -------------
__global__ __launch_bounds__(1024) void k_scan2(int* __restrict__ blk2, int* __restrict__ rowptr2){
  __shared__ int ts[1024];
  int tid = threadIdx.x;
  int s0 = 2*tid, s1 = 2*tid+1;
  int a = 0, b = 0;
  for (int q = 0; q < PB2; ++q){ a += blk2[(size_t)q*2*BB + s0]; b += blk2[(size_t)q*2*BB + s1]; }
  int pair = a + b;
  ts[tid] = pair;
  __syncthreads();
  for (int o = 1; o < 1024; o <<= 1){
    int v = (tid >= o) ? ts[tid-o] : 0;
    __syncthreads();
    ts[tid] += v;
    __syncthreads();
  }
  int incl = ts[tid];
  int excl = incl - pair;
  rowptr2[s0] = excl;
  rowptr2[s1] = excl + a;
  if (tid == 1023) rowptr2[2*BB] = incl;
  int run0 = excl, run1 = excl + a;
  for (int q = 0; q < PB2; ++q){
    size_t i0 = (size_t)q*2*BB + s0, i1 = (size_t)q*2*BB + s1;
    int t0 = blk2[i0]; blk2[i0] = run0; run0 += t0;
    int t1 = blk2[i1]; blk2[i1] = run1; run1 += t1;
  }
}

// ---- layer-2 CSR: place with LDS cursors ----------------------------------
__global__ __launch_bounds__(256) void k_place2(const int* __restrict__ eS, const int* __restrict__ eD,
    const float* __restrict__ eWl, const int* __restrict__ cnt,
    const int* __restrict__ slot1, const int* __restrict__ slotS, const float* __restrict__ dinv,
    const int* __restrict__ blk2, int* __restrict__ e2i, float* __restrict__ e2w){
  __shared__ int cur[2*BB];
  int b = blockIdx.x, tid = threadIdx.x;
  int ne = cnt[2]; if (ne > ECAP) ne = ECAP;
  int slice = (ne + PB2 - 1) / PB2;
  int e0 = b*slice, e1 = e0 + slice; if (e1 > ne) e1 = ne;
  const int* src = blk2 + (size_t)b*2*BB;
  for (int i = tid; i < 2*BB; i += 256) cur[i] = src[i];
  __syncthreads();
  for (int k = e0 + tid; k < e1; k += 256){
    int d = eD[k];
    int sd = slotS[d];
    if (sd < 0) continue;
    int s = eS[k];
    int pos = atomicAdd(&cur[sd], 1);
    e2i[pos] = slot1[s];
    e2w[pos] = dinv[s]*dinv[d]*eWl[k];
  }
}

// ---- layer-2 aggregation, owner-computes ----------------------------------
__global__ __launch_bounds__(256) void k_agg2(const int* __restrict__ rowptr2, const int* __restrict__ e2i,
    const float* __restrict__ e2w, const int* __restrict__ cnt,
    const u16* __restrict__ hbuf, float* __restrict__ agg2){
  int lane = threadIdx.x & 63;
  int wid  = (blockIdx.x*blockDim.x + threadIdx.x) >> 6;
  int nwv  = (gridDim.x*blockDim.x) >> 6;
  int nS = cnt[1]; if (nS > 2*BB) nS = 2*BB;
  for (int c = wid; c < nS; c += nwv){
    int r0 = rowptr2[c], r1 = rowptr2[c+1];
    float ax = 0.f, ay = 0.f;
    for (int k = r0; k < r1; ++k){
      int i = e2i[k];
      if (i < 0) continue;
      float w = e2w[k];
      u32 p = *(const u32*)(hbuf + (size_t)i*DD + lane*2);
      ax += w*bf2f((u16)p);
      ay += w*bf2f((u16)(p >> 16));
    }
    float2 res; res.x = ax; res.y = ay;
    *(float2*)(agg2 + (size_t)c*DD + lane*2) = res;
  }
}

// ---- x_g = (agg2 + self) @ w2 ; out = 0.7*sp + 0.3*x_g --------------------
__global__ __launch_bounds__(128) void k_final(const int* __restrict__ idx1, const int* __restrict__ idx2,
    const float* __restrict__ s1p, const float* __restrict__ s2p,
    const float* __restrict__ agg2, const int* __restrict__ slot1, const int* __restrict__ slotS,
    const float* __restrict__ dinv, const u16* __restrict__ hbuf, const float* __restrict__ w2,
    float* __restrict__ out){
  __shared__ float row[DD];
  int t = threadIdx.x;
  u32 wreg[DD/2];
  #pragma unroll
  for (int i = 0; i < DD/2; ++i){
    u32 lo = f2bf(w2[(2*i)*DD + t]);
    u32 hi = f2bf(w2[(2*i+1)*DD + t]);
    wreg[i] = lo | (hi << 16);
  }
  for (int j = blockIdx.x; j < 2*BB; j += gridDim.x){
    int n = (j < BB) ? idx1[j] : idx2[j - BB];
    float di = dinv[n];
    int sl = slot1[n];
    float hv = (sl >= 0) ? bf2f(hbuf[(size_t)sl*DD + t]) : 0.f;
    __syncthreads();
    int ss = slotS[n];
    row[t] = (ss >= 0 ? agg2[(size_t)ss*DD + t] : 0.f) + di*di*hv;
    __syncthreads();
    float acc = 0.f;
    #pragma unroll
    for (int i = 0; i < DD/2; ++i){
      float2 rv = *(const float2*)&row[2*i];
      u32 w = wreg[i];
      acc += rv.x * bf2f((u16)w);
      acc += rv.y * bf2f((u16)(w >> 16));
    }
    float sp = (j < BB) ? s1p[(size_t)j*DD + t] : s2p[(size_t)(j-BB)*DD + t];
    out[(size_t)j*DD + t] = 0.7f*sp + 0.3f*acc;
  }
}

extern "C" void kernel_launch(void* const* d_in, const int* in_sizes, int n_in,
                              void* d_out, int out_size, void* d_ws, size_t ws_size,
                              hipStream_t stream){
  const float* emb  = (const float*)d_in[0];
  const float* s1   = (const float*)d_in[1];
  const float* s2   = (const float*)d_in[2];
  const float* wp   = (const float*)d_in[3];
  const float* w1   = (const float*)d_in[4];
  const float* w2   = (const float*)d_in[5];
  const int* idx1 = (const int*)d_in[6];
  const int* idx2 = (const int*)d_in[7];
  const int* eidx = (const int*)d_in[8];
  const float* ew   = (const float*)d_in[9];
  const int* esrc = eidx;
  const int* edst = eidx + NE;

  char* ws = (char*)d_ws;
  size_t off = 0;
  auto A = [&](size_t b){ size_t r = off; off += (b + 255) & ~(size_t)255; return r; };
  float* dinv  = (float*)(ws + A((size_t)NN*4));
  int* owner   = (int*)  (ws + A((size_t)NN*4));
  int* slot1   = (int*)  (ws + A((size_t)NN*4));
  int* slotS   = (int*)  (ws + A((size_t)NN*4));
  int* list1   = (int*)  (ws + A((size_t)L1CAP*4));
  int* cnt     = (int*)  (ws + A(256));
  int* fc1     = (int*)  (ws + A(256*4));
  int* fcS     = (int*)  (ws + A(256*4));
  int* selCnt  = (int*)  (ws + A((size_t)GSC*4));
  int* selOff  = (int*)  (ws + A((size_t)(GSC+1)*4));
  int* l1Cnt   = (int*)  (ws + A((size_t)GSC*4));
  int* l1Off   = (int*)  (ws + A((size_t)(GSC+1)*4));
  int* cnt1    = (int*)  (ws + A((size_t)SCN*4));
  int* rowptr  = (int*)  (ws + A((size_t)(SCN+1)*4));
  int* rowptr2 = (int*)  (ws + A((size_t)(2*BB+1)*4));
  int* blk2    = (int*)  (ws + A((size_t)PB2*2*BB*4));
  int* eS      = (int*)  (ws + A((size_t)ECAP*4));
  int* eD      = (int*)  (ws + A((size_t)ECAP*4));
  float* eWl   = (float*)(ws + A((size_t)ECAP*4));
  float* s1p   = (float*)(ws + A((size_t)BB*DD*4));
  float* s2p   = (float*)(ws + A((size_t)BB*DD*4));
  float* pp    = (float*)(ws + A((size_t)KS*2*BB*DD*4));   // 4 MB proj partials
  int* eL1s    = (int*)  (ws + A((size_t)L1ECAP*4));
  int* eL1c    = (int*)  (ws + A((size_t)L1ECAP*4));
  float* eL1w  = (float*)(ws + A((size_t)L1ECAP*4));
  // union1: slcA+slcB (dead after k_compact) overlaid by eCs/eCw/e2i/e2w
  size_t slcB1 = (size_t)GSC*CAPS*4;
  size_t ovl   = (size_t)L1ECAP*4*2 + (size_t)ECAP*4*2;
  size_t u1 = 2*slcB1 > ovl ? 2*slcB1 : ovl;
  char* uni1 = ws + A(u1);
  int* slcA   = (int*)uni1;
  int* slcB   = (int*)(uni1 + slcB1);
  int* eCs    = (int*)uni1;
  float* eCw  = (float*)(uni1 + (size_t)L1ECAP*4);
  int* e2i    = (int*)(uni1 + (size_t)L1ECAP*8);
  float* e2w  = (float*)(uni1 + (size_t)L1ECAP*8 + (size_t)ECAP*4);
  // union2: partial (dead after k_dinv) / blk (cnt1..place) / agg1 (agg1..gemm1)
  size_t partB = (size_t)NCH*DEGB*CH*4;
  size_t blkB  = (size_t)NSCH*PB*SLOTCH*4;
  size_t aggB  = (size_t)L1CAP*DD*4;
  size_t u2 = partB; if (blkB > u2) u2 = blkB; if (aggB > u2) u2 = aggB;
  char* uni2 = ws + A(u2);
  float* partial = (float*)uni2;
  int* blk    = (int*)uni2;
  float* agg1 = (float*)uni2;
  u16*  hbuf  = (u16*) (ws + A((size_t)L1CAP*DD*2));
  float* agg2 = (float*)(ws + A((size_t)2*BB*DD*4));
  (void)in_sizes; (void)n_in; (void)out_size;
  if (ws_size < off) return;   // diagnostic: leaves out == 0 (absmax ~= 3.0)

  hipMemsetAsync(owner, 0xFF, (size_t)NN*4, stream);
  hipMemsetAsync(slot1, 0xFF, (size_t)NN*4, stream);
  hipMemsetAsync(slotS, 0xFF, (size_t)NN*4, stream);
  hipMemsetAsync(cnt,   0,    256, stream);
  hipMemsetAsync(cnt1,  0,    (size_t)SCN*4, stream);

  k_projp  <<<(2*BB/PR)*KS, 128, 0, stream>>>(s1, s2, wp, pp);
  k_projr  <<<(2*BB*DD)/256, 256, 0, stream>>>(pp, s1p, s2p);
  k_mark   <<<8, 256, 0, stream>>>(idx1, idx2, owner, slot1, slotS);
  k_degp   <<<NCH*DEGB, 256, 0, stream>>>(edst, ew, partial);
  k_scansel<<<GSC, 256, 0, stream>>>(esrc, edst, slotS, slot1, selCnt, slcA);
  k_cflag  <<<256, 256, 0, stream>>>(slot1, slotS, fc1, fcS);
  k_asn    <<<256, 64, 0, stream>>>(fc1, fcS, slot1, slotS, list1, cnt);
  k_dinv   <<<(NN+255)/256, 256, 0, stream>>>(partial, dinv);
  k_scanl1 <<<GSC, 256, 0, stream>>>(edst, slot1, l1Cnt, slcB);
  k_escan2 <<<2, 1024, 0, stream>>>(selCnt, selOff, l1Cnt, l1Off, cnt);
  k_compact<<<2*GSC, 128, 0, stream>>>(slcA, slcB, selCnt, selOff, l1Cnt, l1Off,
                                       esrc, edst, ew, dinv, slot1,
                                       eS, eD, eWl, eL1s, eL1c, eL1w);
  k_cnt1   <<<NSCH*PB, 256, 0, stream>>>(eL1c, cnt, cnt1, blk);
  k_scanex <<<1, 1024, 0, stream>>>(cnt1, rowptr);
  k_off    <<<(SCN+255)/256, 256, 0, stream>>>(cnt, rowptr, blk);
  k_place  <<<NSCH*PB, 256, 0, stream>>>(eL1s, eL1c, eL1w, cnt, blk, eCs, eCw);
  k_agg1   <<<2048, 256, 0, stream>>>(rowptr, eCs, eCw, cnt, list1, dinv, owner, emb, s1p, s2p, agg1);
  k_gemm1  <<<2048, 128, 0, stream>>>(agg1, list1, cnt, w1, dinv, owner, emb, s1p, s2p, hbuf);
  k_cnt2   <<<PB2, 256, 0, stream>>>(eD, cnt, slotS, blk2);
  k_scan2  <<<1, 1024, 0, stream>>>(blk2, rowptr2);
  k_place2 <<<PB2, 256, 0, stream>>>(eS, eD, eWl, cnt, slot1, slotS, dinv, blk2, e2i, e2w);
  k_agg2   <<<512, 256, 0, stream>>>(rowptr2, e2i, e2w, cnt, hbuf, agg2);
  k_final  <<<256, 128, 0, stream>>>(idx1, idx2, s1p, s2p, agg2, slot1, slotS, dinv, hbuf, w2, (float*)d_out);
}